// Round 16
// baseline (1795.014 us; speedup 1.0000x reference)
//
#include <hip/hip_runtime.h>

#define Bn  16
#define Ln  256
#define D0n 64
#define Hn  128
#define H4n 512
#define Kn  512
#define BLn 4096   // Bn*Ln

typedef float f4 __attribute__((ext_vector_type(4)));
typedef unsigned long long u64;

__device__ __forceinline__ float sigf(float x) { return 1.0f / (1.0f + expf(-x)); }

__device__ __forceinline__ float fma4v(f4 w, f4 x, float acc) {
    acc = fmaf(w.x, x.x, acc);
    acc = fmaf(w.y, x.y, acc);
    acc = fmaf(w.z, x.z, acc);
    acc = fmaf(w.w, x.w, acc);
    return acc;
}

__device__ __forceinline__ float dotn(const f4* __restrict__ a,
                                      const f4* __restrict__ w, int n4) {
    float a0 = 0.f, a1 = 0.f, a2 = 0.f, a3 = 0.f;
    for (int i = 0; i < n4; i += 4) {
        a0 = fma4v(a[i], w[i], a0);
        a1 = fma4v(a[i + 1], w[i + 1], a1);
        a2 = fma4v(a[i + 2], w[i + 2], a2);
        a3 = fma4v(a[i + 3], w[i + 3], a3);
    }
    return (a0 + a1) + (a2 + a3);
}

// tagged-payload helpers: (tag<<32) | float bits, single 8B relaxed atomic.
// PROTOCOL INVARIANT: a thread must issue its tag_store BEFORE entering any
// tag_poll spin, in straight-line code (no divergent store/poll split within
// a wave) -- R15 violated this and deadlocked.
__device__ __forceinline__ void tag_store(u64* p, float v, unsigned tag) {
    u64 pk = ((u64)tag << 32) | (u64)__float_as_uint(v);
    __hip_atomic_store(p, pk, __ATOMIC_RELAXED, __HIP_MEMORY_SCOPE_AGENT);
}
__device__ __forceinline__ float tag_poll(u64* p, unsigned tag) {
    u64 v;
    do {
        v = __hip_atomic_load(p, __ATOMIC_RELAXED, __HIP_MEMORY_SCOPE_AGENT);
    } while ((unsigned)(v >> 32) != tag);
    return __uint_as_float((unsigned)v);
}

// ---- tiled GEMM v2: k-major LDS tile (conflict-free scalar reads) ----------
__global__ __launch_bounds__(256)
void k_gemm(const float* __restrict__ X, const float* __restrict__ W,
            const float* __restrict__ b, float* __restrict__ Y,
            int K, int out_dim, int do_relu, float scale) {
    __shared__ float wtT[16384];          // k-major: [K][64], K<=256
    const int K4 = K >> 2;
    const int tid = threadIdx.x;
    const int c = tid & 63, rpart = tid >> 6;
    const f4* W4 = (const f4*)W;
    const int per = K4 >> 2;
    for (int j = 0; j < per; ++j) {
        int col = rpart * per + j;
        f4 v = W4[(size_t)(blockIdx.x * 64 + c) * K4 + col];
        wtT[(col * 4 + 0) * 64 + c] = v.x;
        wtT[(col * 4 + 1) * 64 + c] = v.y;
        wtT[(col * 4 + 2) * 64 + c] = v.z;
        wtT[(col * 4 + 3) * 64 + c] = v.w;
    }
    __syncthreads();
    const f4* X4 = (const f4*)X;
    const float bc = b ? b[blockIdx.x * 64 + c] : 0.f;
    for (int i = 0; i < 16; ++i) {
        int r = blockIdx.y * 64 + i * 4 + rpart;
        const f4* xr = X4 + (size_t)r * K4;
        float a0 = 0.f, a1 = 0.f, a2 = 0.f, a3 = 0.f;
        for (int k4 = 0; k4 < K4; ++k4) {
            f4 xv = xr[k4];                       // wave-uniform
            a0 = fmaf(xv.x, wtT[(k4 * 4 + 0) * 64 + c], a0);
            a1 = fmaf(xv.y, wtT[(k4 * 4 + 1) * 64 + c], a1);
            a2 = fmaf(xv.z, wtT[(k4 * 4 + 2) * 64 + c], a2);
            a3 = fmaf(xv.w, wtT[(k4 * 4 + 3) * 64 + c], a3);
        }
        float acc = scale * ((a0 + a1) + (a2 + a3)) + bc;
        if (do_relu) acc = fmaxf(acc, 0.f);
        Y[(size_t)r * out_dim + blockIdx.x * 64 + c] = acc;
    }
}

// ---- fused prep: WqT | WihL(4-side) | WhhL | w1L | zero tags ---------------
__global__ void k_prep(const float* __restrict__ attn_Wq, float* __restrict__ WqT,
                       const f4* __restrict__ dec_Wih, f4* __restrict__ WihL,
                       const f4* __restrict__ whf, const f4* __restrict__ whb,
                       f4* __restrict__ WhhL,
                       const f4* __restrict__ dec_W1, f4* __restrict__ w1L,
                       int* __restrict__ zbuf, int zcount) {
    const int blk = blockIdx.x, tid = threadIdx.x;
    if (blk < 64) {                        // WqT[c][r] = Wq[r][c], 128x128
        int idx = blk * 256 + tid;
        int c = idx >> 7, r = idx & 127;
        WqT[idx] = attn_Wq[(size_t)r * Hn + c];
    } else if (blk < 128) {                // WihL[s][k][tid], s<4,k<16,tid<256
        int idx = (blk - 64) * 256 + tid;  // 16384
        int t = idx & 255, k = (idx >> 8) & 15, s = idx >> 12;
        int rl = t >> 1;
        int grow = (rl >> 5) * 128 + s * 32 + (rl & 31);
        WihL[idx] = dec_Wih[(size_t)grow * 32 + (t & 1) * 16 + k];
    } else if (blk < 192) {                // WhhL[dir][k][row] = Whh[row][16+k]
        int idx = (blk - 128) * 256 + tid; // 16384
        int row = idx & 511, k = (idx >> 9) & 15, dir = idx >> 13;
        const f4* src = dir ? whb : whf;
        WhhL[idx] = src[(size_t)row * 32 + 16 + k];
    } else if (blk < 200) {                // w1L[k][t] = W1[t>>1][(t&1)*8+k]
        int idx = (blk - 192) * 256 + tid; // 2048
        int t = idx & 255, k = idx >> 8;
        w1L[idx] = dec_W1[((size_t)(t >> 1)) * 16 + (t & 1) * 8 + k];
    } else {                               // zero tag space
        int idx = (blk - 200) * 256 + tid;
        if (idx < zcount) zbuf[idx] = 0;
    }
}

// ---- KQL[(b*4+s)][k][tid] = kq[b*256+s*64+(tid>>2)][(tid&3)*8+k] (f4) ------
__global__ void k_rearrKQL(const f4* __restrict__ in, f4* __restrict__ out) {
    int idx = blockIdx.x * blockDim.x + threadIdx.x;   // 131072
    if (idx >= 131072) return;
    int tid = idx & 255, k = (idx >> 8) & 7, bs = idx >> 11;
    int row = (bs >> 2) * 256 + (bs & 3) * 64 + (tid >> 2);
    out[idx] = in[(size_t)row * 32 + (tid & 3) * 8 + k];
}

// -------- cst[p] = scale*(bq . kp[p]) + (mask[p]==0 ? -1e9 : 0) --------
__global__ void k_cst(const float* __restrict__ kp, const float* __restrict__ bq,
                      const float* __restrict__ mask, float* __restrict__ cst) {
    int p = blockIdx.x * blockDim.x + threadIdx.x;
    if (p >= BLn) return;
    float a = dotn((const f4*)bq, (const f4*)(kp + (size_t)p * Hn), Hn >> 2);
    cst[p] = a * 0.088388347648318447f + (mask[p] == 0.f ? -1e9f : 0.f);
}

// -------- codebook squared norms --------
__global__ void k_codenorm(const float* __restrict__ emb, float* __restrict__ c2) {
    int k = blockIdx.x * blockDim.x + threadIdx.x;
    if (k >= Kn) return;
    const f4* e4 = (const f4*)(emb + (size_t)k * Hn);
    float acc = 0.f;
    for (int i = 0; i < Hn / 4; ++i) {
        f4 v = e4[i];
        acc = fmaf(v.x, v.x, acc); acc = fmaf(v.y, v.y, acc);
        acc = fmaf(v.z, v.z, acc); acc = fmaf(v.w, v.w, acc);
    }
    c2[k] = acc;
}

// -------- VQ pick: argmin over dist row (first-index ties) + gather ---------
__global__ __launch_bounds__(128)
void k_vqpick(const float* __restrict__ dist, const float* __restrict__ emb,
              float* __restrict__ zq) {
    const int p = blockIdx.x, tid = threadIdx.x;
    __shared__ int best_s;
    if (tid < 64) {
        float best = 3.0e38f; int bi = 0;
        for (int j = 0; j < 8; ++j) {
            int k = j * 64 + tid;
            float d = dist[(size_t)p * Kn + k];
            if (d < best) { best = d; bi = k; }
        }
        for (int off = 32; off > 0; off >>= 1) {
            float ov = __shfl_xor(best, off);
            int   oi = __shfl_xor(bi, off);
            if (ov < best || (ov == best && oi < bi)) { best = ov; bi = oi; }
        }
        if (tid == 0) best_s = bi;
    }
    __syncthreads();
    zq[(size_t)p * Hn + tid] = emb[(size_t)best_s * Hn + tid];
}

// -------- LSTM v3: ONE block per (batch,dir), 512 thr (proven R12) ----------
__global__ __launch_bounds__(512, 1)
void k_lstm3(const float* __restrict__ xWf, const float* __restrict__ xWb,
             const float* __restrict__ Whh_f, const float* __restrict__ Whh_b,
             const float* __restrict__ WhhL_g, float* __restrict__ hcat) {
    const int b   = blockIdx.x & 15;
    const int dir = blockIdx.x >> 4;
    const int tid = threadIdx.x;               // = gate row
    const float* xW  = dir ? xWb : xWf;
    const f4* Whh4   = (const f4*)(dir ? Whh_b : Whh_f);

    __shared__ __align__(16) f4 wh2_s[16 * 512];   // 128 KB second halves
    __shared__ __align__(16) float h_s[Hn];
    __shared__ float g_s[H4n];

    f4 w[16];
#pragma unroll
    for (int f = 0; f < 16; ++f) w[f] = Whh4[(size_t)tid * 32 + f];
#pragma unroll
    for (int f = 0; f < 16; ++f) asm volatile("" : "+v"(w[f]));

    const f4* WhhL4 = (const f4*)WhhL_g;
#pragma unroll
    for (int k = 0; k < 16; ++k)
        wh2_s[k * 512 + tid] = WhhL4[(size_t)dir * 8192 + k * 512 + tid];

    float c_reg = 0.f;
    if (tid < Hn) h_s[tid] = 0.f;

    const int t0 = dir ? (Ln - 1) : 0;
    float xw_v = xW[((size_t)b * Ln + t0) * H4n + tid];
    __syncthreads();

    for (int s = 0; s < Ln; ++s) {
        const int t = dir ? (Ln - 1 - s) : s;
        float xw_n = 0.f;
        if (s + 1 < Ln) {
            int tn = dir ? (Ln - 2 - s) : (s + 1);
            xw_n = xW[((size_t)b * Ln + tn) * H4n + tid];
        }
        {
            const f4* h4 = (const f4*)h_s;
            float a0 = 0.f, a1 = 0.f, a2 = 0.f, a3 = 0.f;
#pragma unroll
            for (int f = 0; f < 16; f += 4) {
                a0 = fma4v(w[f],     h4[f],     a0);
                a1 = fma4v(w[f + 1], h4[f + 1], a1);
                a2 = fma4v(w[f + 2], h4[f + 2], a2);
                a3 = fma4v(w[f + 3], h4[f + 3], a3);
            }
#pragma unroll
            for (int f = 0; f < 16; f += 4) {
                a0 = fma4v(wh2_s[f * 512 + tid],       h4[16 + f],     a0);
                a1 = fma4v(wh2_s[(f + 1) * 512 + tid], h4[16 + f + 1], a1);
                a2 = fma4v(wh2_s[(f + 2) * 512 + tid], h4[16 + f + 2], a2);
                a3 = fma4v(wh2_s[(f + 3) * 512 + tid], h4[16 + f + 3], a3);
            }
            g_s[tid] = (a0 + a1) + (a2 + a3) + xw_v;
        }
        __syncthreads();
        if (tid < Hn) {
            float ig = sigf(g_s[tid]);
            float fg = sigf(g_s[Hn + tid]);
            float gg = tanhf(g_s[2 * Hn + tid]);
            float og = sigf(g_s[3 * Hn + tid]);
            c_reg = fg * c_reg + ig * gg;
            float hv = og * tanhf(c_reg);
            h_s[tid] = hv;
            hcat[((size_t)b * Ln + t) * (2 * Hn) + dir * Hn + tid] = hv;
        }
        __syncthreads();
        xw_v = xw_n;
    }
}

// -------- decoder v4b: 4 blocks/batch x 256 thr; ALL loop data in LDS -------
// Deadlock-safe exchange: every thread stores BEFORE it polls (same lane,
// straight-line). 7 barriers/step, 2 tagged exchanges (h 32f, P/m/Z 66f).
__global__ __launch_bounds__(256, 1)
void k_decoder(const float* __restrict__ kqL_g, const float* __restrict__ vw_g,
               const float* __restrict__ cst_g,
               const float* __restrict__ w1L_g, const float* __restrict__ b1_g,
               const float* __restrict__ WihL_g, const float* __restrict__ Whh,
               const float* __restrict__ bd_g,
               u64* gxh, u64* gxp,
               float* __restrict__ dec_out, float* __restrict__ attn_w) {
    const int b   = blockIdx.x & 15;
    const int s   = blockIdx.x >> 4;      // {b,b+16,b+32,b+48} same XCD
    const int tid = threadIdx.x;

    __shared__ __align__(16) f4 wih_s[4096];     // 64 KB [k<16][256]
    __shared__ __align__(16) f4 kq_s[2048];      // 32 KB [k<8][256]
    __shared__ __align__(16) f4 w1_s[2048];      // 32 KB [k<8][256]
    __shared__ __align__(16) float tok_s[D0n];
    __shared__ __align__(16) float x_s[Hn];
    __shared__ __align__(16) float h_s[Hn];
    __shared__ float g_loc[Hn];
    __shared__ float s_loc[64];
    __shared__ float pP[4][72];
    __shared__ float peermz[8];
    __shared__ float cst_s[64];
    __shared__ float b1_s[Hn];

    const int rl = tid >> 1, ghalf = tid & 1;    // 128 rows x 2 thr (A,B)
    const int grow = (rl >> 5) * 128 + s * 32 + (rl & 31);
    const int wavep = tid >> 6, lane = tid & 63; // E/F maps

    // ---- pinned regs ----
    const f4* Whh4 = (const f4*)Whh;
    f4 whh[16];
#pragma unroll
    for (int f = 0; f < 16; ++f) whh[f] = Whh4[(size_t)grow * 32 + ghalf * 16 + f];
    float bdr = bd_g[grow];
    float vwr[16];                               // VW[s*64+wavep*16+k][lane]
#pragma unroll
    for (int k = 0; k < 16; ++k)
        vwr[k] = vw_g[((size_t)b * Ln + s * 64 + wavep * 16 + k) * D0n + lane];
#pragma unroll
    for (int f = 0; f < 16; ++f) asm volatile("" : "+v"(whh[f]));
#pragma unroll
    for (int k = 0; k < 16; ++k) asm volatile("" : "+v"(vwr[k]));
    asm volatile("" : "+v"(bdr));

    // ---- stage LDS (all lane-contiguous) ----
    const f4* WihL4 = (const f4*)WihL_g;
#pragma unroll
    for (int k = 0; k < 16; ++k)
        wih_s[k * 256 + tid] = WihL4[(size_t)s * 4096 + k * 256 + tid];
    const f4* kqL4 = (const f4*)kqL_g;
#pragma unroll
    for (int k = 0; k < 8; ++k)
        kq_s[k * 256 + tid] = kqL4[(size_t)(b * 4 + s) * 2048 + k * 256 + tid];
    const f4* w1L4 = (const f4*)w1L_g;
#pragma unroll
    for (int k = 0; k < 8; ++k)
        w1_s[k * 256 + tid] = w1L4[k * 256 + tid];
    if (tid < D0n) tok_s[tid] = 0.f;
    if (tid < Hn)  { h_s[tid] = 0.f; b1_s[tid] = b1_g[tid]; }
    if (tid < 64)  cst_s[tid] = cst_g[(size_t)b * Ln + s * 64 + tid];
    float c_reg = 0.f;
    __syncthreads();

    u64* gxh_mine = gxh + (size_t)((b * 4 + s) * 2) * 32;
    u64* gxp_mine = gxp + (size_t)((b * 4 + s) * 2) * 66;
    const int sp1 = (s + 1) & 3, sp2 = (s + 2) & 3, sp3 = (s + 3) & 3;

    for (int t = 0; t < Ln; ++t) {
        const unsigned tg = (unsigned)(t + 1);
        const int par = t & 1;
        // ---- A: x = relu(W1@tok + b1); 128 rows x 2 thr, W1 in LDS ----
        {
            const f4* t4 = (const f4*)tok_s;
            float u0 = 0.f, u1 = 0.f;
#pragma unroll
            for (int k = 0; k < 8; k += 2) {
                u0 = fma4v(w1_s[k * 256 + tid],       t4[ghalf * 8 + k],     u0);
                u1 = fma4v(w1_s[(k + 1) * 256 + tid], t4[ghalf * 8 + k + 1], u1);
            }
            float a = u0 + u1;
            a += __shfl_xor(a, 1);
            if (ghalf == 0) x_s[rl] = fmaxf(a + b1_s[rl], 0.f);
        }
        __syncthreads();
        // ---- B: gates own 128 rows; Wih LDS + whh pinned ----
        {
            const f4* x4 = (const f4*)x_s + ghalf * 16;
            const f4* h4 = (const f4*)h_s + ghalf * 16;
            float a0 = 0.f, a1 = 0.f, a2 = 0.f, a3 = 0.f;
#pragma unroll
            for (int f = 0; f < 16; f += 4) {
                a0 = fma4v(wih_s[f * 256 + tid],       x4[f],     a0);
                a1 = fma4v(wih_s[(f + 1) * 256 + tid], x4[f + 1], a1);
                a2 = fma4v(wih_s[(f + 2) * 256 + tid], x4[f + 2], a2);
                a3 = fma4v(wih_s[(f + 3) * 256 + tid], x4[f + 3], a3);
            }
#pragma unroll
            for (int f = 0; f < 16; f += 4) {
                a0 = fma4v(whh[f],     h4[f],     a0);
                a1 = fma4v(whh[f + 1], h4[f + 1], a1);
                a2 = fma4v(whh[f + 2], h4[f + 2], a2);
                a3 = fma4v(whh[f + 3], h4[f + 3], a3);
            }
            float a = (a0 + a1) + (a2 + a3);
            a += __shfl_xor(a, 1);
            if (ghalf == 0) g_loc[rl] = a + bdr;
        }
        __syncthreads();
        // ---- C: cell (thr<32): store own h THEN poll 3 peers (same lane) ---
        if (tid < 32) {
            float ig = sigf(g_loc[tid]);
            float fg = sigf(g_loc[32 + tid]);
            float gg = tanhf(g_loc[64 + tid]);
            float og = sigf(g_loc[96 + tid]);
            c_reg = fg * c_reg + ig * gg;
            float hv = og * tanhf(c_reg);
            h_s[s * 32 + tid] = hv;
            tag_store(&gxh_mine[par * 32 + tid], hv, tg);
            h_s[sp1 * 32 + tid] = tag_poll(
                gxh + (size_t)((b * 4 + sp1) * 2 + par) * 32 + tid, tg);
            h_s[sp2 * 32 + tid] = tag_poll(
                gxh + (size_t)((b * 4 + sp2) * 2 + par) * 32 + tid, tg);
            h_s[sp3 * 32 + tid] = tag_poll(
                gxh + (size_t)((b * 4 + sp3) * 2 + par) * 32 + tid, tg);
        }
        __syncthreads();
        // ---- D: scores own 64 l; KQ in LDS, 4 thr/l ----
        {
            const int ll = tid >> 2, dp = tid & 3;
            const f4* h4 = (const f4*)h_s;
            float u0 = 0.f, u1 = 0.f;
#pragma unroll
            for (int k = 0; k < 8; k += 2) {
                u0 = fma4v(kq_s[k * 256 + tid],       h4[dp * 8 + k],     u0);
                u1 = fma4v(kq_s[(k + 1) * 256 + tid], h4[dp * 8 + k + 1], u1);
            }
            float a = u0 + u1;
            a += __shfl_xor(a, 1);
            a += __shfl_xor(a, 2);
            if (dp == 0) s_loc[ll] = a + cst_s[ll];
        }
        __syncthreads();
        // ---- E: per-wave redundant local softmax + partial P ----
        float e, m_own, Z_own;
        {
            float v = s_loc[lane];
            float m = v;
#pragma unroll
            for (int o2 = 32; o2 > 0; o2 >>= 1) m = fmaxf(m, __shfl_xor(m, o2));
            e = expf(v - m);
            float Z = e;
#pragma unroll
            for (int o2 = 32; o2 > 0; o2 >>= 1) Z += __shfl_xor(Z, o2);
            m_own = m; Z_own = Z;
            float acc = 0.f;
#pragma unroll
            for (int k = 0; k < 16; ++k)
                acc = fmaf(__shfl(e, wavep * 16 + k), vwr[k], acc);
            pP[wavep][lane] = acc;
        }
        __syncthreads();
        // ---- E2: store own (P|m|Z) THEN poll peers (same lanes) ----
        float Pown = 0.f, p1 = 0.f, p2 = 0.f, p3 = 0.f;
        if (tid < 64) {        // wave 0: P store then 3 polls, straight-line
            Pown = pP[0][tid] + pP[1][tid] + pP[2][tid] + pP[3][tid];
            tag_store(&gxp_mine[par * 66 + tid], Pown, tg);
            p1 = tag_poll(gxp + (size_t)((b * 4 + sp1) * 2 + par) * 66 + tid, tg);
            p2 = tag_poll(gxp + (size_t)((b * 4 + sp2) * 2 + par) * 66 + tid, tg);
            p3 = tag_poll(gxp + (size_t)((b * 4 + sp3) * 2 + par) * 66 + tid, tg);
        } else if (tid < 70) { // wave 1 lanes 0..5: m/Z stores precede polls
            int idx = tid - 64;            // 0..5
            if (idx == 0) tag_store(&gxp_mine[par * 66 + 64], m_own, tg);
            if (idx == 1) tag_store(&gxp_mine[par * 66 + 65], Z_own, tg);
            int spi = idx >> 1, which = idx & 1;
            int sp = (s + 1 + spi) & 3;
            peermz[idx] = tag_poll(
                gxp + (size_t)((b * 4 + sp) * 2 + par) * 66 + 64 + which, tg);
        }
        __syncthreads();
        // ---- F: global softmax combine -> out, attn slice, next tok ----
        if (tid < 64) {
            float m1 = peermz[0], Z1 = peermz[1];
            float m2 = peermz[2], Z2 = peermz[3];
            float m3 = peermz[4], Z3 = peermz[5];
            float M = fmaxf(fmaxf(m_own, m1), fmaxf(m2, m3));
            float w0 = expf(m_own - M), w1 = expf(m1 - M);
            float w2 = expf(m2 - M), w3 = expf(m3 - M);
            float inv = 1.f / (w0 * Z_own + w1 * Z1 + w2 * Z2 + w3 * Z3);
            float ov = (w0 * Pown + w1 * p1 + w2 * p2 + w3 * p3) * inv;
            tok_s[tid] = ov;
            if (s == 0) dec_out[((size_t)b * Ln + t) * D0n + tid] = ov;
            attn_w[((size_t)b * Ln + t) * Ln + s * 64 + tid] = e * w0 * inv;
        }
        __syncthreads();
    }
}

extern "C" void kernel_launch(void* const* d_in, const int* in_sizes, int n_in,
                              void* d_out, int out_size, void* d_ws, size_t ws_size,
                              hipStream_t stream) {
    const float* inputs     = (const float*)d_in[0];
    const float* in_mask    = (const float*)d_in[2];
    const float* enc_lin1_W = (const float*)d_in[3];
    const float* enc_lin1_b = (const float*)d_in[4];
    const float* enc_Wih_f  = (const float*)d_in[5];
    const float* enc_Whh_f  = (const float*)d_in[6];
    const float* enc_b_f    = (const float*)d_in[7];
    const float* enc_Wih_b  = (const float*)d_in[8];
    const float* enc_Whh_b  = (const float*)d_in[9];
    const float* enc_b_b    = (const float*)d_in[10];
    const float* enc_lin2_W = (const float*)d_in[11];
    const float* enc_lin2_b = (const float*)d_in[12];
    const float* vq_emb     = (const float*)d_in[13];
    const float* dec_lin1_W = (const float*)d_in[14];
    const float* dec_lin1_b = (const float*)d_in[15];
    const float* dec_Wih    = (const float*)d_in[16];
    const float* dec_Whh    = (const float*)d_in[17];
    const float* dec_b      = (const float*)d_in[18];
    const float* attn_Wq    = (const float*)d_in[19];
    const float* attn_bq    = (const float*)d_in[20];
    const float* attn_Wk    = (const float*)d_in[21];
    const float* attn_bk    = (const float*)d_in[22];
    const float* attn_Wv    = (const float*)d_in[23];
    const float* attn_bv    = (const float*)d_in[24];
    const float* dec_lin2_W = (const float*)d_in[25];
    const float* dec_lin2_b = (const float*)d_in[26];

    float* out     = (float*)d_out;
    float* dec_out = out;                       // 16*256*64   = 262144
    float* attn_w  = out + 262144;              // 16*256*256  = 1048576
    float* ze      = out + 1310720;             // 16*256*128  = 524288
    float* zq      = out + 1835008;             // 16*256*128  = 524288

    float* ws    = (float*)d_ws;
    float* enc_x = ws;                          // 524288
    float* xWf   = enc_x + 524288;              // 2097152
    float* xWb   = xWf + 2097152;               // 2097152
    float* hcat  = xWb + 2097152;               // 1048576
    float* kp    = hcat + 1048576;              // 524288
    float* vp    = kp + 524288;                 // 524288
    float* c2    = vp + 524288;                 // 512
    u64*   gxh   = (u64*)(c2 + 512);            // 16*4*2*32 = 4096 u64
    u64*   gxp   = gxh + 4096;                  // 16*4*2*66 = 8448 u64
    // tag space: 12544 u64 = 25088 ints, zeroed in k_prep each launch
    // aliases into dead regions:
    float* WqT   = enc_x;                       // 16384 (enc_x dead after xW GEMMs)
    float* WihL  = enc_x + 16384;               // 65536 floats = 16384 f4
    float* WhhL  = enc_x + 16384 + 65536;       // 65536 floats = 16384 f4
    float* w1L   = enc_x + 16384 + 2 * 65536;   // 8192 floats = 2048 f4
    float* dist  = xWf;                         // 2097152 (dead after vqpick)
    float* KQL   = xWf;                         // 131072 f4 = 524288 floats
    float* kq    = xWb;                         // 524288  (xWb dead post-LSTM)
    float* vw    = xWb + 524288;                // 262144
    float* cst   = xWb + 786432;                // 4096

    dim3 blk(256);
    // ---- encoder front ----
    k_gemm<<<dim3(2, 64), blk, 0, stream>>>(inputs, enc_lin1_W, enc_lin1_b, enc_x, D0n, Hn, 1, 1.f);
    k_gemm<<<dim3(8, 64), blk, 0, stream>>>(enc_x, enc_Wih_f, enc_b_f, xWf, Hn, H4n, 0, 1.f);
    k_gemm<<<dim3(8, 64), blk, 0, stream>>>(enc_x, enc_Wih_b, enc_b_b, xWb, Hn, H4n, 0, 1.f);
    // ---- fused prep ----
    k_prep<<<298, 256, 0, stream>>>(attn_Wq, WqT, (const f4*)dec_Wih, (f4*)WihL,
                                    (const f4*)enc_Whh_f, (const f4*)enc_Whh_b,
                                    (f4*)WhhL, (const f4*)dec_lin1_W, (f4*)w1L,
                                    (int*)gxh, 25088);
    // ---- BiLSTM ----
    k_lstm3<<<32, 512, 0, stream>>>(xWf, xWb, enc_Whh_f, enc_Whh_b, WhhL, hcat);
    k_gemm<<<dim3(2, 64), blk, 0, stream>>>(hcat, enc_lin2_W, enc_lin2_b, ze, 2 * Hn, Hn, 0, 1.f);
    // ---- VQ ----
    k_codenorm<<<2, 256, 0, stream>>>(vq_emb, c2);
    k_gemm<<<dim3(8, 64), blk, 0, stream>>>(ze, vq_emb, c2, dist, Hn, Kn, 0, -2.f);
    k_vqpick<<<BLn, 128, 0, stream>>>(dist, vq_emb, zq);
    // ---- attention precomputes (dec_in == zq) ----
    k_gemm<<<dim3(2, 64), blk, 0, stream>>>(zq, attn_Wk, attn_bk, kp, Hn, Hn, 0, 1.f);
    k_gemm<<<dim3(2, 64), blk, 0, stream>>>(zq, attn_Wv, attn_bv, vp, Hn, Hn, 0, 1.f);
    k_gemm<<<dim3(2, 64), blk, 0, stream>>>(kp, WqT, nullptr, kq, Hn, Hn, 0, 0.088388347648318447f);
    k_rearrKQL<<<512, 256, 0, stream>>>((const f4*)kq, (f4*)KQL);
    k_gemm<<<dim3(1, 64), blk, 0, stream>>>(vp, dec_lin2_W, dec_lin2_b, vw, Hn, D0n, 0, 1.f);
    k_cst<<<Bn, 256, 0, stream>>>(kp, attn_bq, in_mask, cst);
    // ---- decoder: 64 blocks = 16 batches x 4 sides, 256 thr ----
    k_decoder<<<64, 256, 0, stream>>>(KQL, vw, cst,
                                      w1L, dec_lin1_b,
                                      WihL, dec_Whh, dec_b,
                                      gxh, gxp,
                                      dec_out, attn_w);
}

// Round 17
// 1670.534 us; speedup vs baseline: 1.0745x; 1.0745x over previous
//
#include <hip/hip_runtime.h>

#define Bn  16
#define Ln  256
#define D0n 64
#define Hn  128
#define H4n 512
#define Kn  512
#define BLn 4096   // Bn*Ln

typedef float f4 __attribute__((ext_vector_type(4)));
typedef unsigned long long u64;

__device__ __forceinline__ float sigf(float x) { return 1.0f / (1.0f + expf(-x)); }

__device__ __forceinline__ float fma4v(f4 w, f4 x, float acc) {
    acc = fmaf(w.x, x.x, acc);
    acc = fmaf(w.y, x.y, acc);
    acc = fmaf(w.z, x.z, acc);
    acc = fmaf(w.w, x.w, acc);
    return acc;
}

__device__ __forceinline__ float dotn(const f4* __restrict__ a,
                                      const f4* __restrict__ w, int n4) {
    float a0 = 0.f, a1 = 0.f, a2 = 0.f, a3 = 0.f;
    for (int i = 0; i < n4; i += 4) {
        a0 = fma4v(a[i], w[i], a0);
        a1 = fma4v(a[i + 1], w[i + 1], a1);
        a2 = fma4v(a[i + 2], w[i + 2], a2);
        a3 = fma4v(a[i + 3], w[i + 3], a3);
    }
    return (a0 + a1) + (a2 + a3);
}

// tagged-payload helpers: (tag<<32) | float bits, single 8B relaxed atomic.
// PROTOCOL INVARIANT: a thread must issue its tag_store BEFORE entering any
// tag_poll spin, in straight-line code within the same lane.
__device__ __forceinline__ void tag_store(u64* p, float v, unsigned tag) {
    u64 pk = ((u64)tag << 32) | (u64)__float_as_uint(v);
    __hip_atomic_store(p, pk, __ATOMIC_RELAXED, __HIP_MEMORY_SCOPE_AGENT);
}
__device__ __forceinline__ float tag_poll(u64* p, unsigned tag) {
    u64 v;
    do {
        v = __hip_atomic_load(p, __ATOMIC_RELAXED, __HIP_MEMORY_SCOPE_AGENT);
    } while ((unsigned)(v >> 32) != tag);
    return __uint_as_float((unsigned)v);
}

// ---- tiled GEMM v3: [k4][c] f4 tile, lane-contiguous b128, 4-row blocking --
// Y[r][c] = scale*(X[r].W[c]) + b[c]; tile 64r x 64c; block 256 (4 waves).
// One LDS b128 read feeds 16 FMAs (4 rows). X loads wave-uniform (broadcast).
__global__ __launch_bounds__(256)
void k_gemm(const float* __restrict__ X, const float* __restrict__ W,
            const float* __restrict__ b, float* __restrict__ Y,
            int K, int out_dim, int do_relu, float scale) {
    __shared__ __align__(16) f4 wt4[4096];   // [k4][64], K<=256 -> 64 KB max
    const int K4 = K >> 2;
    const int tid = threadIdx.x;
    const int c = tid & 63, rpart = tid >> 6;
    const f4* W4 = (const f4*)W;
    const int per = K4 >> 2;                 // K4/4 cols per wave
    for (int j = 0; j < per; ++j) {
        int col = rpart * per + j;
        wt4[col * 64 + c] = W4[(size_t)(blockIdx.x * 64 + c) * K4 + col];
    }
    __syncthreads();
    const f4* X4 = (const f4*)X;
    const float bc = b ? b[blockIdx.x * 64 + c] : 0.f;
    const int cidx = blockIdx.x * 64 + c;
    for (int i = 0; i < 4; ++i) {
        int rbase = blockIdx.y * 64 + i * 16 + rpart * 4;
        const f4* xr0 = X4 + (size_t)(rbase + 0) * K4;
        const f4* xr1 = X4 + (size_t)(rbase + 1) * K4;
        const f4* xr2 = X4 + (size_t)(rbase + 2) * K4;
        const f4* xr3 = X4 + (size_t)(rbase + 3) * K4;
        float a0 = 0.f, a1 = 0.f, a2 = 0.f, a3 = 0.f;
        for (int k4 = 0; k4 < K4; ++k4) {
            f4 wv = wt4[k4 * 64 + c];        // lane-contiguous b128
            a0 = fma4v(wv, xr0[k4], a0);
            a1 = fma4v(wv, xr1[k4], a1);
            a2 = fma4v(wv, xr2[k4], a2);
            a3 = fma4v(wv, xr3[k4], a3);
        }
        a0 = scale * a0 + bc; a1 = scale * a1 + bc;
        a2 = scale * a2 + bc; a3 = scale * a3 + bc;
        if (do_relu) {
            a0 = fmaxf(a0, 0.f); a1 = fmaxf(a1, 0.f);
            a2 = fmaxf(a2, 0.f); a3 = fmaxf(a3, 0.f);
        }
        Y[(size_t)(rbase + 0) * out_dim + cidx] = a0;
        Y[(size_t)(rbase + 1) * out_dim + cidx] = a1;
        Y[(size_t)(rbase + 2) * out_dim + cidx] = a2;
        Y[(size_t)(rbase + 3) * out_dim + cidx] = a3;
    }
}

// ---- fused prep: WqT transpose | WihL rearr | WhhL rearr | zero tags ------
__global__ void k_prep(const float* __restrict__ attn_Wq, float* __restrict__ WqT,
                       const f4* __restrict__ dec_Wih, f4* __restrict__ WihL,
                       const f4* __restrict__ whf, const f4* __restrict__ whb,
                       f4* __restrict__ WhhL, int* __restrict__ zbuf) {
    const int blk = blockIdx.x, tid = threadIdx.x;
    if (blk < 64) {                        // WqT[c][r] = Wq[r][c], 128x128
        int idx = blk * 256 + tid;
        int c = idx >> 7, r = idx & 127;
        WqT[idx] = attn_Wq[(size_t)r * Hn + c];
    } else if (blk < 128) {                // WihL[k*1024 + side*512 + t]
        int idx = (blk - 64) * 256 + tid;  // 16384
        int t = idx & 511, side = (idx >> 9) & 1, k = idx >> 10;
        int rl = t >> 1;
        int grow = (rl >> 6) * 128 + side * 64 + (rl & 63);
        WihL[idx] = dec_Wih[(size_t)grow * 32 + (t & 1) * 16 + k];
    } else if (blk < 192) {                // WhhL[dir][k][row] = Whh[row][16+k]
        int idx = (blk - 128) * 256 + tid; // 16384
        int row = idx & 511, k = (idx >> 9) & 15, dir = idx >> 13;
        const f4* src = dir ? whb : whf;
        WhhL[idx] = src[(size_t)row * 32 + 16 + k];
    } else {                               // zero 8192 ints of tag space
        int idx = (blk - 192) * 256 + tid;
        if (idx < 8192) zbuf[idx] = 0;
    }
}

// ---- KQF[b][k][tid] = kq[b*256 + (tid>>1)][(tid&1)*16 + k], f4 ----
__global__ void k_rearrKQF(const f4* __restrict__ in, f4* __restrict__ out) {
    int idx = blockIdx.x * blockDim.x + threadIdx.x;   // 131072
    if (idx >= 131072) return;
    int tid = idx & 511, k = (idx >> 9) & 15, b = idx >> 13;
    out[idx] = in[((size_t)b * 256 + (tid >> 1)) * 32 + (tid & 1) * 16 + k];
}

// -------- cst[p] = scale*(bq . kp[p]) + (mask[p]==0 ? -1e9 : 0) --------
__global__ void k_cst(const float* __restrict__ kp, const float* __restrict__ bq,
                      const float* __restrict__ mask, float* __restrict__ cst) {
    int p = blockIdx.x * blockDim.x + threadIdx.x;
    if (p >= BLn) return;
    float a = dotn((const f4*)bq, (const f4*)(kp + (size_t)p * Hn), Hn >> 2);
    cst[p] = a * 0.088388347648318447f + (mask[p] == 0.f ? -1e9f : 0.f);
}

// -------- codebook squared norms --------
__global__ void k_codenorm(const float* __restrict__ emb, float* __restrict__ c2) {
    int k = blockIdx.x * blockDim.x + threadIdx.x;
    if (k >= Kn) return;
    const f4* e4 = (const f4*)(emb + (size_t)k * Hn);
    float acc = 0.f;
    for (int i = 0; i < Hn / 4; ++i) {
        f4 v = e4[i];
        acc = fmaf(v.x, v.x, acc); acc = fmaf(v.y, v.y, acc);
        acc = fmaf(v.z, v.z, acc); acc = fmaf(v.w, v.w, acc);
    }
    c2[k] = acc;
}

// -------- VQ pick: argmin over dist row (first-index ties) + gather ---------
__global__ __launch_bounds__(128)
void k_vqpick(const float* __restrict__ dist, const float* __restrict__ emb,
              float* __restrict__ zq) {
    const int p = blockIdx.x, tid = threadIdx.x;
    __shared__ int best_s;
    if (tid < 64) {
        float best = 3.0e38f; int bi = 0;
        for (int j = 0; j < 8; ++j) {
            int k = j * 64 + tid;
            float d = dist[(size_t)p * Kn + k];
            if (d < best) { best = d; bi = k; }
        }
        for (int off = 32; off > 0; off >>= 1) {
            float ov = __shfl_xor(best, off);
            int   oi = __shfl_xor(bi, off);
            if (ov < best || (ov == best && oi < bi)) { best = ov; bi = oi; }
        }
        if (tid == 0) best_s = bi;
    }
    __syncthreads();
    zq[(size_t)p * Hn + tid] = emb[(size_t)best_s * Hn + tid];
}

// -------- LSTM v3: ONE block per (batch,dir), 512 thr, 1 thread/row ---------
__global__ __launch_bounds__(512, 1)
void k_lstm3(const float* __restrict__ xWf, const float* __restrict__ xWb,
             const float* __restrict__ Whh_f, const float* __restrict__ Whh_b,
             const float* __restrict__ WhhL_g, float* __restrict__ hcat) {
    const int b   = blockIdx.x & 15;
    const int dir = blockIdx.x >> 4;
    const int tid = threadIdx.x;               // = gate row
    const float* xW  = dir ? xWb : xWf;
    const f4* Whh4   = (const f4*)(dir ? Whh_b : Whh_f);

    __shared__ __align__(16) f4 wh2_s[16 * 512];   // 128 KB second halves
    __shared__ __align__(16) float h_s[Hn];
    __shared__ float g_s[H4n];

    f4 w[16];
#pragma unroll
    for (int f = 0; f < 16; ++f) w[f] = Whh4[(size_t)tid * 32 + f];
#pragma unroll
    for (int f = 0; f < 16; ++f) asm volatile("" : "+v"(w[f]));

    const f4* WhhL4 = (const f4*)WhhL_g;
#pragma unroll
    for (int k = 0; k < 16; ++k)
        wh2_s[k * 512 + tid] = WhhL4[(size_t)dir * 8192 + k * 512 + tid];

    float c_reg = 0.f;
    if (tid < Hn) h_s[tid] = 0.f;

    const int t0 = dir ? (Ln - 1) : 0;
    float xw_v = xW[((size_t)b * Ln + t0) * H4n + tid];
    __syncthreads();

    for (int s = 0; s < Ln; ++s) {
        const int t = dir ? (Ln - 1 - s) : s;
        float xw_n = 0.f;
        if (s + 1 < Ln) {
            int tn = dir ? (Ln - 2 - s) : (s + 1);
            xw_n = xW[((size_t)b * Ln + tn) * H4n + tid];
        }
        {
            const f4* h4 = (const f4*)h_s;
            float a0 = 0.f, a1 = 0.f, a2 = 0.f, a3 = 0.f;
#pragma unroll
            for (int f = 0; f < 16; f += 4) {
                a0 = fma4v(w[f],     h4[f],     a0);
                a1 = fma4v(w[f + 1], h4[f + 1], a1);
                a2 = fma4v(w[f + 2], h4[f + 2], a2);
                a3 = fma4v(w[f + 3], h4[f + 3], a3);
            }
#pragma unroll
            for (int f = 0; f < 16; f += 4) {
                a0 = fma4v(wh2_s[f * 512 + tid],       h4[16 + f],     a0);
                a1 = fma4v(wh2_s[(f + 1) * 512 + tid], h4[16 + f + 1], a1);
                a2 = fma4v(wh2_s[(f + 2) * 512 + tid], h4[16 + f + 2], a2);
                a3 = fma4v(wh2_s[(f + 3) * 512 + tid], h4[16 + f + 3], a3);
            }
            g_s[tid] = (a0 + a1) + (a2 + a3) + xw_v;
        }
        __syncthreads();
        if (tid < Hn) {
            float ig = sigf(g_s[tid]);
            float fg = sigf(g_s[Hn + tid]);
            float gg = tanhf(g_s[2 * Hn + tid]);
            float og = sigf(g_s[3 * Hn + tid]);
            c_reg = fg * c_reg + ig * gg;
            float hv = og * tanhf(c_reg);
            h_s[tid] = hv;
            hcat[((size_t)b * Ln + t) * (2 * Hn) + dir * Hn + tid] = hv;
        }
        __syncthreads();
        xw_v = xw_n;
    }
}

// -------- decoder (R11/R14 proven): 2 blocks/batch x 512 thr; 6 barriers ----
// A | B | C(cell+tagged exch) | D | E(softmax) | F(out).
// Pinned: whh 16f4 (64) + vwr 32 + bdr = 97. Wih in LDS 128KB. KQ/W1 streamed.
__global__ __launch_bounds__(512, 1)
void k_decoder(const float* __restrict__ kqF_g, const float* __restrict__ vw_g,
               const float* __restrict__ cst_g,
               const float* __restrict__ W1,  const float* __restrict__ b1_g,
               const float* __restrict__ WihL_g, const float* __restrict__ Whh,
               const float* __restrict__ bd_g, u64* gxd,
               float* __restrict__ dec_out, float* __restrict__ attn_w) {
    const int b    = blockIdx.x & 15;
    const int side = blockIdx.x >> 4;     // b and b+16 same XCD
    const int tid  = threadIdx.x;

    __shared__ __align__(16) f4 wih_s[16 * 512];   // 128 KB, lane-contiguous
    __shared__ __align__(16) float tok_s[D0n];
    __shared__ __align__(16) float x_s[Hn];
    __shared__ __align__(16) float h_s[Hn];
    __shared__ float g_loc[256];
    __shared__ float s_s[Ln];
    __shared__ float attn_sp[8][33];               // padded (slab-major)
    __shared__ float cst_s[Ln];
    __shared__ float b1_s[Hn];

    const int rl = tid >> 1, ghalf = tid & 1;      // gates: 256 rows x 2 thr
    const int grow = (rl >> 6) * 128 + side * 64 + (rl & 63);

    // ---- pinned: whh half-row + VW slice + bias ----
    const f4* Whh4 = (const f4*)Whh;
    f4 whh[16];
#pragma unroll
    for (int f = 0; f < 16; ++f) whh[f] = Whh4[(size_t)grow * 32 + ghalf * 16 + f];
    float bdr = bd_g[grow];
    const int o = tid >> 3, slab = tid & 7;        // out phase map
    float vwr[32];
#pragma unroll
    for (int l = 0; l < 32; ++l)
        vwr[l] = vw_g[((size_t)b * Ln + slab * 32 + l) * D0n + o];
#pragma unroll
    for (int f = 0; f < 16; ++f) asm volatile("" : "+v"(whh[f]));
#pragma unroll
    for (int l = 0; l < 32; ++l) asm volatile("" : "+v"(vwr[l]));
    asm volatile("" : "+v"(bdr));

    // ---- stage Wih into LDS (coalesced both ends) ----
    const f4* WihL4 = (const f4*)WihL_g;
#pragma unroll
    for (int k = 0; k < 16; ++k)
        wih_s[k * 512 + tid] = WihL4[(size_t)k * 1024 + side * 512 + tid];
    if (tid < D0n) tok_s[tid] = 0.f;
    if (tid < Hn)  { h_s[tid] = 0.f; b1_s[tid] = b1_g[tid]; }
    if (tid < Ln)  cst_s[tid] = cst_g[(size_t)b * Ln + tid];
    float c_reg = 0.f;
    __syncthreads();

    u64* gx_mine = gxd + (b * 2 + side) * 128;
    u64* gx_peer = gxd + (b * 2 + (side ^ 1)) * 128;

    const int ar = tid >> 2, ap = tid & 3;         // x phase: 128 rows x 4 thr
    const f4* W1_4 = (const f4*)W1;
    const f4* kqF  = (const f4*)kqF_g + (size_t)b * 8192;
    const int dbase = (tid & 1) * 16;              // score phase h offset

    for (int t = 0; t < Ln; ++t) {
        // ---- A: x = relu(W1 @ tok + b1); W1 streamed (L2-hot) ----
        {
            const f4* t4 = (const f4*)tok_s;
            float u0 = 0.f, u1 = 0.f;
#pragma unroll
            for (int k = 0; k < 4; k += 2) {
                f4 wa  = W1_4[(size_t)ar * 16 + ap * 4 + k];
                f4 wb2 = W1_4[(size_t)ar * 16 + ap * 4 + k + 1];
                u0 = fma4v(wa,  t4[ap * 4 + k],     u0);
                u1 = fma4v(wb2, t4[ap * 4 + k + 1], u1);
            }
            float a = u0 + u1;
            a += __shfl_xor(a, 1);
            a += __shfl_xor(a, 2);
            if (ap == 0) x_s[ar] = fmaxf(a + b1_s[ar], 0.f);
        }
        __syncthreads();
        // ---- B: gates; Wih from LDS (lane-contig), Whh pinned ----
        {
            const f4* x4 = (const f4*)x_s + ghalf * 16;
            const f4* h4 = (const f4*)h_s + ghalf * 16;
            float a0 = 0.f, a1 = 0.f, a2 = 0.f, a3 = 0.f;
#pragma unroll
            for (int f = 0; f < 16; f += 4) {
                a0 = fma4v(wih_s[f * 512 + tid],       x4[f],     a0);
                a1 = fma4v(wih_s[(f + 1) * 512 + tid], x4[f + 1], a1);
                a2 = fma4v(wih_s[(f + 2) * 512 + tid], x4[f + 2], a2);
                a3 = fma4v(wih_s[(f + 3) * 512 + tid], x4[f + 3], a3);
            }
#pragma unroll
            for (int f = 0; f < 16; f += 4) {
                a0 = fma4v(whh[f],     h4[f],     a0);
                a1 = fma4v(whh[f + 1], h4[f + 1], a1);
                a2 = fma4v(whh[f + 2], h4[f + 2], a2);
                a3 = fma4v(whh[f + 3], h4[f + 3], a3);
            }
            float a = (a0 + a1) + (a2 + a3);
            a += __shfl_xor(a, 1);
            if (ghalf == 0) g_loc[rl] = a + bdr;
        }
        __syncthreads();
        // ---- C: cell (own 64) + tagged publish + poll peer (fused) ----
        if (tid < 64) {
            float ig = sigf(g_loc[tid]);
            float fg = sigf(g_loc[64 + tid]);
            float gg = tanhf(g_loc[128 + tid]);
            float og = sigf(g_loc[192 + tid]);
            c_reg = fg * c_reg + ig * gg;
            float hv = og * tanhf(c_reg);
            h_s[side * 64 + tid] = hv;
            tag_store(&gx_mine[(t & 1) * 64 + tid], hv, (unsigned)(t + 1));
            h_s[(side ^ 1) * 64 + tid] =
                tag_poll(&gx_peer[(t & 1) * 64 + tid], (unsigned)(t + 1));
        }
        __syncthreads();
        // ---- D: scores; KQ streamed coalesced from L2 (L2-hot) ----
        {
            const f4* h4 = (const f4*)h_s;
            float a0 = 0.f, a1 = 0.f;
#pragma unroll
            for (int k = 0; k < 16; k += 2) {
                f4 q0 = kqF[(size_t)k * 512 + tid];
                f4 q1 = kqF[(size_t)(k + 1) * 512 + tid];
                a0 = fma4v(q0, h4[dbase + k],     a0);
                a1 = fma4v(q1, h4[dbase + k + 1], a1);
            }
            float a = a0 + a1;
            a += __shfl_xor(a, 1);
            if ((tid & 1) == 0) s_s[tid >> 1] = a + cst_s[tid >> 1];
        }
        __syncthreads();
        // ---- E: softmax (wave 0); side 0 writes attn_w ----
        if (tid < 64) {
            float v0 = s_s[tid],       v1 = s_s[tid + 64];
            float v2 = s_s[tid + 128], v3 = s_s[tid + 192];
            float m = fmaxf(fmaxf(v0, v1), fmaxf(v2, v3));
#pragma unroll
            for (int o2 = 32; o2 > 0; o2 >>= 1) m = fmaxf(m, __shfl_xor(m, o2));
            float e0 = expf(v0 - m), e1 = expf(v1 - m);
            float e2 = expf(v2 - m), e3 = expf(v3 - m);
            float ss = (e0 + e1) + (e2 + e3);
#pragma unroll
            for (int o2 = 32; o2 > 0; o2 >>= 1) ss += __shfl_xor(ss, o2);
            float inv = 1.f / ss;
            e0 *= inv; e1 *= inv; e2 *= inv; e3 *= inv;
            attn_sp[tid >> 5][tid & 31] = e0;
            attn_sp[(tid + 64) >> 5][tid & 31] = e1;
            attn_sp[(tid + 128) >> 5][tid & 31] = e2;
            attn_sp[(tid + 192) >> 5][tid & 31] = e3;
            if (side == 0) {
                float* aw = attn_w + ((size_t)b * Ln + t) * Ln;
                aw[tid] = e0; aw[tid + 64] = e1;
                aw[tid + 128] = e2; aw[tid + 192] = e3;
            }
        }
        __syncthreads();
        // ---- F: out[o] = sum_l attn[l]*VW'[l][o]; 64 o x 8 slabs ----
        {
            const float* as = attn_sp[slab];
            float g0 = 0.f, g1 = 0.f, g2 = 0.f, g3 = 0.f;
#pragma unroll
            for (int l = 0; l < 32; l += 4) {
                g0 = fmaf(as[l],     vwr[l],     g0);
                g1 = fmaf(as[l + 1], vwr[l + 1], g1);
                g2 = fmaf(as[l + 2], vwr[l + 2], g2);
                g3 = fmaf(as[l + 3], vwr[l + 3], g3);
            }
            float a = (g0 + g1) + (g2 + g3);
            a += __shfl_xor(a, 1);
            a += __shfl_xor(a, 2);
            a += __shfl_xor(a, 4);
            if (slab == 0) {
                tok_s[o] = a;
                if (side == 1) dec_out[((size_t)b * Ln + t) * D0n + o] = a;
            }
        }
        __syncthreads();
    }
}

extern "C" void kernel_launch(void* const* d_in, const int* in_sizes, int n_in,
                              void* d_out, int out_size, void* d_ws, size_t ws_size,
                              hipStream_t stream) {
    const float* inputs     = (const float*)d_in[0];
    const float* in_mask    = (const float*)d_in[2];
    const float* enc_lin1_W = (const float*)d_in[3];
    const float* enc_lin1_b = (const float*)d_in[4];
    const float* enc_Wih_f  = (const float*)d_in[5];
    const float* enc_Whh_f  = (const float*)d_in[6];
    const float* enc_b_f    = (const float*)d_in[7];
    const float* enc_Wih_b  = (const float*)d_in[8];
    const float* enc_Whh_b  = (const float*)d_in[9];
    const float* enc_b_b    = (const float*)d_in[10];
    const float* enc_lin2_W = (const float*)d_in[11];
    const float* enc_lin2_b = (const float*)d_in[12];
    const float* vq_emb     = (const float*)d_in[13];
    const float* dec_lin1_W = (const float*)d_in[14];
    const float* dec_lin1_b = (const float*)d_in[15];
    const float* dec_Wih    = (const float*)d_in[16];
    const float* dec_Whh    = (const float*)d_in[17];
    const float* dec_b      = (const float*)d_in[18];
    const float* attn_Wq    = (const float*)d_in[19];
    const float* attn_bq    = (const float*)d_in[20];
    const float* attn_Wk    = (const float*)d_in[21];
    const float* attn_bk    = (const float*)d_in[22];
    const float* attn_Wv    = (const float*)d_in[23];
    const float* attn_bv    = (const float*)d_in[24];
    const float* dec_lin2_W = (const float*)d_in[25];
    const float* dec_lin2_b = (const float*)d_in[26];

    float* out     = (float*)d_out;
    float* dec_out = out;                       // 16*256*64   = 262144
    float* attn_w  = out + 262144;              // 16*256*256  = 1048576
    float* ze      = out + 1310720;             // 16*256*128  = 524288
    float* zq      = out + 1835008;             // 16*256*128  = 524288

    float* ws    = (float*)d_ws;
    float* enc_x = ws;                          // 524288
    float* xWf   = enc_x + 524288;              // 2097152
    float* xWb   = xWf + 2097152;               // 2097152
    float* hcat  = xWb + 2097152;               // 1048576
    float* kp    = hcat + 1048576;              // 524288
    float* vp    = kp + 524288;                 // 524288
    float* c2    = vp + 524288;                 // 512
    u64*   gxd   = (u64*)(c2 + 512);            // 32*128 u64 = 4096 u64
    // aliases into dead regions:
    float* WqT   = enc_x;                       // 16384 (enc_x dead after xW GEMMs)
    float* WihL  = enc_x + 16384;               // 65536 floats = 16384 f4
    float* WhhL  = enc_x + 16384 + 65536;       // 65536 floats = 16384 f4
    float* dist  = xWf;                         // 2097152 (dead after vqpick)
    float* KQF   = xWf;                         // 131072 f4 = 524288 floats
    float* kq    = xWb;                         // 524288  (xWb dead post-LSTM)
    float* vw    = xWb + 524288;                // 262144
    float* cst   = xWb + 786432;                // 4096

    dim3 blk(256);
    // ---- encoder front ----
    k_gemm<<<dim3(2, 64), blk, 0, stream>>>(inputs, enc_lin1_W, enc_lin1_b, enc_x, D0n, Hn, 1, 1.f);
    k_gemm<<<dim3(8, 64), blk, 0, stream>>>(enc_x, enc_Wih_f, enc_b_f, xWf, Hn, H4n, 0, 1.f);
    k_gemm<<<dim3(8, 64), blk, 0, stream>>>(enc_x, enc_Wih_b, enc_b_b, xWb, Hn, H4n, 0, 1.f);
    // ---- fused prep: WqT | WihL | WhhL | zero tags ----
    k_prep<<<224, 256, 0, stream>>>(attn_Wq, WqT, (const f4*)dec_Wih, (f4*)WihL,
                                    (const f4*)enc_Whh_f, (const f4*)enc_Whh_b,
                                    (f4*)WhhL, (int*)gxd);
    // ---- BiLSTM: 32 blocks = 16b x 2dir, single-block (no exchange) ----
    k_lstm3<<<32, 512, 0, stream>>>(xWf, xWb, enc_Whh_f, enc_Whh_b, WhhL, hcat);
    k_gemm<<<dim3(2, 64), blk, 0, stream>>>(hcat, enc_lin2_W, enc_lin2_b, ze, 2 * Hn, Hn, 0, 1.f);
    // ---- VQ ----
    k_codenorm<<<2, 256, 0, stream>>>(vq_emb, c2);
    k_gemm<<<dim3(8, 64), blk, 0, stream>>>(ze, vq_emb, c2, dist, Hn, Kn, 0, -2.f);
    k_vqpick<<<BLn, 128, 0, stream>>>(dist, vq_emb, zq);
    // ---- attention precomputes (dec_in == zq) ----
    k_gemm<<<dim3(2, 64), blk, 0, stream>>>(zq, attn_Wk, attn_bk, kp, Hn, Hn, 0, 1.f);
    k_gemm<<<dim3(2, 64), blk, 0, stream>>>(zq, attn_Wv, attn_bv, vp, Hn, Hn, 0, 1.f);
    k_gemm<<<dim3(2, 64), blk, 0, stream>>>(kp, WqT, nullptr, kq, Hn, Hn, 0, 0.088388347648318447f);
    k_rearrKQF<<<512, 256, 0, stream>>>((const f4*)kq, (f4*)KQF);
    k_gemm<<<dim3(1, 64), blk, 0, stream>>>(vp, dec_lin2_W, dec_lin2_b, vw, Hn, D0n, 0, 1.f);
    k_cst<<<Bn, 256, 0, stream>>>(kp, attn_bq, in_mask, cst);
    // ---- decoder: 32 blocks = 16 batches x 2 sides, 512 thr ----
    k_decoder<<<32, 512, 0, stream>>>(KQF, vw, cst,
                                      dec_lin1_W, dec_lin1_b,
                                      WihL, dec_Whh, dec_b, gxd,
                                      dec_out, attn_w);
}

// Round 18
// 1590.358 us; speedup vs baseline: 1.1287x; 1.0504x over previous
//
#include <hip/hip_runtime.h>

#define Bn  16
#define Ln  256
#define D0n 64
#define Hn  128
#define H4n 512
#define Kn  512
#define BLn 4096   // Bn*Ln

typedef float f4 __attribute__((ext_vector_type(4)));
typedef unsigned long long u64;

__device__ __forceinline__ float sigf(float x) { return 1.0f / (1.0f + expf(-x)); }

__device__ __forceinline__ float fma4v(f4 w, f4 x, float acc) {
    acc = fmaf(w.x, x.x, acc);
    acc = fmaf(w.y, x.y, acc);
    acc = fmaf(w.z, x.z, acc);
    acc = fmaf(w.w, x.w, acc);
    return acc;
}

__device__ __forceinline__ float dotn(const f4* __restrict__ a,
                                      const f4* __restrict__ w, int n4) {
    float a0 = 0.f, a1 = 0.f, a2 = 0.f, a3 = 0.f;
    for (int i = 0; i < n4; i += 4) {
        a0 = fma4v(a[i], w[i], a0);
        a1 = fma4v(a[i + 1], w[i + 1], a1);
        a2 = fma4v(a[i + 2], w[i + 2], a2);
        a3 = fma4v(a[i + 3], w[i + 3], a3);
    }
    return (a0 + a1) + (a2 + a3);
}

// tagged-payload helpers: (tag<<32) | float bits, single 8B relaxed atomic.
// PROTOCOL INVARIANT: a thread must issue its tag_store BEFORE entering any
// tag_poll spin, in straight-line code within the same lane.
__device__ __forceinline__ void tag_store(u64* p, float v, unsigned tag) {
    u64 pk = ((u64)tag << 32) | (u64)__float_as_uint(v);
    __hip_atomic_store(p, pk, __ATOMIC_RELAXED, __HIP_MEMORY_SCOPE_AGENT);
}
__device__ __forceinline__ float tag_poll(u64* p, unsigned tag) {
    u64 v;
    do {
        v = __hip_atomic_load(p, __ATOMIC_RELAXED, __HIP_MEMORY_SCOPE_AGENT);
    } while ((unsigned)(v >> 32) != tag);
    return __uint_as_float((unsigned)v);
}

// ---- tiled GEMM v3: [k4][c] f4 tile, lane-contiguous b128, 4-row blocking --
__global__ __launch_bounds__(256)
void k_gemm(const float* __restrict__ X, const float* __restrict__ W,
            const float* __restrict__ b, float* __restrict__ Y,
            int K, int out_dim, int do_relu, float scale) {
    __shared__ __align__(16) f4 wt4[4096];   // [k4][64], K<=256
    const int K4 = K >> 2;
    const int tid = threadIdx.x;
    const int c = tid & 63, rpart = tid >> 6;
    const f4* W4 = (const f4*)W;
    const int per = K4 >> 2;
    for (int j = 0; j < per; ++j) {
        int col = rpart * per + j;
        wt4[col * 64 + c] = W4[(size_t)(blockIdx.x * 64 + c) * K4 + col];
    }
    __syncthreads();
    const f4* X4 = (const f4*)X;
    const float bc = b ? b[blockIdx.x * 64 + c] : 0.f;
    const int cidx = blockIdx.x * 64 + c;
    for (int i = 0; i < 4; ++i) {
        int rbase = blockIdx.y * 64 + i * 16 + rpart * 4;
        const f4* xr0 = X4 + (size_t)(rbase + 0) * K4;
        const f4* xr1 = X4 + (size_t)(rbase + 1) * K4;
        const f4* xr2 = X4 + (size_t)(rbase + 2) * K4;
        const f4* xr3 = X4 + (size_t)(rbase + 3) * K4;
        float a0 = 0.f, a1 = 0.f, a2 = 0.f, a3 = 0.f;
        for (int k4 = 0; k4 < K4; ++k4) {
            f4 wv = wt4[k4 * 64 + c];
            a0 = fma4v(wv, xr0[k4], a0);
            a1 = fma4v(wv, xr1[k4], a1);
            a2 = fma4v(wv, xr2[k4], a2);
            a3 = fma4v(wv, xr3[k4], a3);
        }
        a0 = scale * a0 + bc; a1 = scale * a1 + bc;
        a2 = scale * a2 + bc; a3 = scale * a3 + bc;
        if (do_relu) {
            a0 = fmaxf(a0, 0.f); a1 = fmaxf(a1, 0.f);
            a2 = fmaxf(a2, 0.f); a3 = fmaxf(a3, 0.f);
        }
        Y[(size_t)(rbase + 0) * out_dim + cidx] = a0;
        Y[(size_t)(rbase + 1) * out_dim + cidx] = a1;
        Y[(size_t)(rbase + 2) * out_dim + cidx] = a2;
        Y[(size_t)(rbase + 3) * out_dim + cidx] = a3;
    }
}

// ---- dual-weight GEMM: z=0 -> (Wf,bf,Yf), z=1 -> (Wb,bb,Yb); same shape ----
__global__ __launch_bounds__(256)
void k_gemm2(const float* __restrict__ X,
             const float* __restrict__ Wf, const float* __restrict__ bf,
             float* __restrict__ Yf,
             const float* __restrict__ Wb, const float* __restrict__ bb,
             float* __restrict__ Yb, int K, int out_dim) {
    __shared__ __align__(16) f4 wt4[4096];
    const float* W = blockIdx.z ? Wb : Wf;
    const float* bb_ = blockIdx.z ? bb : bf;
    float* Y = blockIdx.z ? Yb : Yf;
    const int K4 = K >> 2;
    const int tid = threadIdx.x;
    const int c = tid & 63, rpart = tid >> 6;
    const f4* W4 = (const f4*)W;
    const int per = K4 >> 2;
    for (int j = 0; j < per; ++j) {
        int col = rpart * per + j;
        wt4[col * 64 + c] = W4[(size_t)(blockIdx.x * 64 + c) * K4 + col];
    }
    __syncthreads();
    const f4* X4 = (const f4*)X;
    const float bc = bb_[blockIdx.x * 64 + c];
    const int cidx = blockIdx.x * 64 + c;
    for (int i = 0; i < 4; ++i) {
        int rbase = blockIdx.y * 64 + i * 16 + rpart * 4;
        const f4* xr0 = X4 + (size_t)(rbase + 0) * K4;
        const f4* xr1 = X4 + (size_t)(rbase + 1) * K4;
        const f4* xr2 = X4 + (size_t)(rbase + 2) * K4;
        const f4* xr3 = X4 + (size_t)(rbase + 3) * K4;
        float a0 = 0.f, a1 = 0.f, a2 = 0.f, a3 = 0.f;
        for (int k4 = 0; k4 < K4; ++k4) {
            f4 wv = wt4[k4 * 64 + c];
            a0 = fma4v(wv, xr0[k4], a0);
            a1 = fma4v(wv, xr1[k4], a1);
            a2 = fma4v(wv, xr2[k4], a2);
            a3 = fma4v(wv, xr3[k4], a3);
        }
        Y[(size_t)(rbase + 0) * out_dim + cidx] = a0 + bc;
        Y[(size_t)(rbase + 1) * out_dim + cidx] = a1 + bc;
        Y[(size_t)(rbase + 2) * out_dim + cidx] = a2 + bc;
        Y[(size_t)(rbase + 3) * out_dim + cidx] = a3 + bc;
    }
}

#define SCL 0.088388347648318447f   // 1/sqrt(128)

// ---- k_prep: ALL weight algebra + codebook norms + tag zeroing -------------
// blk 0..63   : Wcat[c][d]   = SCL * sum_r Wq[r][c]*Wk[r][d]      (M, 16384)
// blk 64..95  : Wcat[128+o][d] = sum_r W2[o][r]*Wv[r][d]          (Mv, 8192)
// blk 96..159 : WihL rearr (16384)
// blk 160..223: WhhL rearr (16384)
// blk 224     : bcat: kb[c]=SCL*sum Wq[r][c]*bk[r]; bv2[o]=W2.bv+b2
// blk 225     : u[d]=SCL*sum bq[r]*Wk[r][d]; ub=SCL*(bq.bk)
// blk 226..227: c2 codebook norms (512)
// blk 228..259: zero 8192 ints of tag space
__global__ void k_prep(const float* __restrict__ Wq, const float* __restrict__ Wk,
                       const float* __restrict__ Wv, const float* __restrict__ W2,
                       const float* __restrict__ bk, const float* __restrict__ bv,
                       const float* __restrict__ b2, const float* __restrict__ bq,
                       float* __restrict__ Wcat, float* __restrict__ bcat,
                       float* __restrict__ u, float* __restrict__ ub,
                       const f4* __restrict__ dec_Wih, f4* __restrict__ WihL,
                       const f4* __restrict__ whf, const f4* __restrict__ whb,
                       f4* __restrict__ WhhL,
                       const float* __restrict__ emb, float* __restrict__ c2,
                       int* __restrict__ zbuf) {
    const int blk = blockIdx.x, tid = threadIdx.x;
    if (blk < 64) {
        int idx = blk * 256 + tid;
        int c = idx >> 7, d = idx & 127;
        float acc = 0.f;
        for (int r = 0; r < Hn; ++r)
            acc = fmaf(Wq[(size_t)r * Hn + c], Wk[(size_t)r * Hn + d], acc);
        Wcat[(size_t)c * Hn + d] = SCL * acc;
    } else if (blk < 96) {
        int idx = (blk - 64) * 256 + tid;
        int o = idx >> 7, d = idx & 127;
        float acc = 0.f;
        for (int r = 0; r < Hn; ++r)
            acc = fmaf(W2[(size_t)o * Hn + r], Wv[(size_t)r * Hn + d], acc);
        Wcat[(size_t)(128 + o) * Hn + d] = acc;
    } else if (blk < 160) {                // WihL[k*1024 + side*512 + t]
        int idx = (blk - 96) * 256 + tid;  // 16384
        int t = idx & 511, side = (idx >> 9) & 1, k = idx >> 10;
        int rl = t >> 1;
        int grow = (rl >> 6) * 128 + side * 64 + (rl & 63);
        WihL[idx] = dec_Wih[(size_t)grow * 32 + (t & 1) * 16 + k];
    } else if (blk < 224) {                // WhhL[dir][k][row] = Whh[row][16+k]
        int idx = (blk - 160) * 256 + tid; // 16384
        int row = idx & 511, k = (idx >> 9) & 15, dir = idx >> 13;
        const f4* src = dir ? whb : whf;
        WhhL[idx] = src[(size_t)row * 32 + 16 + k];
    } else if (blk == 224) {
        if (tid < 128) {
            float acc = 0.f;
            for (int r = 0; r < Hn; ++r)
                acc = fmaf(Wq[(size_t)r * Hn + tid], bk[r], acc);
            bcat[tid] = SCL * acc;
        } else if (tid < 192) {
            int o = tid - 128;
            float acc = b2[o];
            for (int r = 0; r < Hn; ++r)
                acc = fmaf(W2[(size_t)o * Hn + r], bv[r], acc);
            bcat[tid] = acc;
        }
    } else if (blk == 225) {
        if (tid < 128) {
            float acc = 0.f;
            for (int r = 0; r < Hn; ++r)
                acc = fmaf(bq[r], Wk[(size_t)r * Hn + tid], acc);
            u[tid] = SCL * acc;
        } else if (tid == 128) {
            float acc = 0.f;
            for (int r = 0; r < Hn; ++r) acc = fmaf(bq[r], bk[r], acc);
            ub[0] = SCL * acc;
        }
    } else if (blk < 228) {
        int k = (blk - 226) * 256 + tid;
        if (k < Kn) {
            const f4* e4 = (const f4*)(emb + (size_t)k * Hn);
            float acc = 0.f;
            for (int i = 0; i < Hn / 4; ++i) {
                f4 v = e4[i];
                acc = fmaf(v.x, v.x, acc); acc = fmaf(v.y, v.y, acc);
                acc = fmaf(v.z, v.z, acc); acc = fmaf(v.w, v.w, acc);
            }
            c2[k] = acc;
        }
    } else {
        int idx = (blk - 228) * 256 + tid;
        if (idx < 8192) zbuf[idx] = 0;
    }
}

// ---- KQF[b][k][tid] = Ycat[b*256 + (tid>>1)][(tid&1)*16 + k], row=48 f4 ----
__global__ void k_rearrKQF(const f4* __restrict__ in, f4* __restrict__ out) {
    int idx = blockIdx.x * blockDim.x + threadIdx.x;   // 131072
    if (idx >= 131072) return;
    int tid = idx & 511, k = (idx >> 9) & 15, b = idx >> 13;
    out[idx] = in[((size_t)b * 256 + (tid >> 1)) * 48 + (tid & 1) * 16 + k];
}

// -------- cst[p] = u . zq[p] + ub + (mask[p]==0 ? -1e9 : 0) --------
__global__ void k_cst(const float* __restrict__ zq, const float* __restrict__ u,
                      const float* __restrict__ ub, const float* __restrict__ mask,
                      float* __restrict__ cst) {
    int p = blockIdx.x * blockDim.x + threadIdx.x;
    if (p >= BLn) return;
    float a = dotn((const f4*)u, (const f4*)(zq + (size_t)p * Hn), Hn >> 2);
    cst[p] = a + ub[0] + (mask[p] == 0.f ? -1e9f : 0.f);
}

// -------- VQ pick: argmin over dist row (first-index ties) + gather ---------
__global__ __launch_bounds__(128)
void k_vqpick(const float* __restrict__ dist, const float* __restrict__ emb,
              float* __restrict__ zq) {
    const int p = blockIdx.x, tid = threadIdx.x;
    __shared__ int best_s;
    if (tid < 64) {
        float best = 3.0e38f; int bi = 0;
        for (int j = 0; j < 8; ++j) {
            int k = j * 64 + tid;
            float d = dist[(size_t)p * Kn + k];
            if (d < best) { best = d; bi = k; }
        }
        for (int off = 32; off > 0; off >>= 1) {
            float ov = __shfl_xor(best, off);
            int   oi = __shfl_xor(bi, off);
            if (ov < best || (ov == best && oi < bi)) { best = ov; bi = oi; }
        }
        if (tid == 0) best_s = bi;
    }
    __syncthreads();
    zq[(size_t)p * Hn + tid] = emb[(size_t)best_s * Hn + tid];
}

// -------- LSTM v3: ONE block per (batch,dir), 512 thr, 1 thread/row ---------
__global__ __launch_bounds__(512, 1)
void k_lstm3(const float* __restrict__ xWf, const float* __restrict__ xWb,
             const float* __restrict__ Whh_f, const float* __restrict__ Whh_b,
             const float* __restrict__ WhhL_g, float* __restrict__ hcat) {
    const int b   = blockIdx.x & 15;
    const int dir = blockIdx.x >> 4;
    const int tid = threadIdx.x;               // = gate row
    const float* xW  = dir ? xWb : xWf;
    const f4* Whh4   = (const f4*)(dir ? Whh_b : Whh_f);

    __shared__ __align__(16) f4 wh2_s[16 * 512];   // 128 KB second halves
    __shared__ __align__(16) float h_s[Hn];
    __shared__ float g_s[H4n];

    f4 w[16];
#pragma unroll
    for (int f = 0; f < 16; ++f) w[f] = Whh4[(size_t)tid * 32 + f];
#pragma unroll
    for (int f = 0; f < 16; ++f) asm volatile("" : "+v"(w[f]));

    const f4* WhhL4 = (const f4*)WhhL_g;
#pragma unroll
    for (int k = 0; k < 16; ++k)
        wh2_s[k * 512 + tid] = WhhL4[(size_t)dir * 8192 + k * 512 + tid];

    float c_reg = 0.f;
    if (tid < Hn) h_s[tid] = 0.f;

    const int t0 = dir ? (Ln - 1) : 0;
    float xw_v = xW[((size_t)b * Ln + t0) * H4n + tid];
    __syncthreads();

    for (int s = 0; s < Ln; ++s) {
        const int t = dir ? (Ln - 1 - s) : s;
        float xw_n = 0.f;
        if (s + 1 < Ln) {
            int tn = dir ? (Ln - 2 - s) : (s + 1);
            xw_n = xW[((size_t)b * Ln + tn) * H4n + tid];
        }
        {
            const f4* h4 = (const f4*)h_s;
            float a0 = 0.f, a1 = 0.f, a2 = 0.f, a3 = 0.f;
#pragma unroll
            for (int f = 0; f < 16; f += 4) {
                a0 = fma4v(w[f],     h4[f],     a0);
                a1 = fma4v(w[f + 1], h4[f + 1], a1);
                a2 = fma4v(w[f + 2], h4[f + 2], a2);
                a3 = fma4v(w[f + 3], h4[f + 3], a3);
            }
#pragma unroll
            for (int f = 0; f < 16; f += 4) {
                a0 = fma4v(wh2_s[f * 512 + tid],       h4[16 + f],     a0);
                a1 = fma4v(wh2_s[(f + 1) * 512 + tid], h4[16 + f + 1], a1);
                a2 = fma4v(wh2_s[(f + 2) * 512 + tid], h4[16 + f + 2], a2);
                a3 = fma4v(wh2_s[(f + 3) * 512 + tid], h4[16 + f + 3], a3);
            }
            g_s[tid] = (a0 + a1) + (a2 + a3) + xw_v;
        }
        __syncthreads();
        if (tid < Hn) {
            float ig = sigf(g_s[tid]);
            float fg = sigf(g_s[Hn + tid]);
            float gg = tanhf(g_s[2 * Hn + tid]);
            float og = sigf(g_s[3 * Hn + tid]);
            c_reg = fg * c_reg + ig * gg;
            float hv = og * tanhf(c_reg);
            h_s[tid] = hv;
            hcat[((size_t)b * Ln + t) * (2 * Hn) + dir * Hn + tid] = hv;
        }
        __syncthreads();
        xw_v = xw_n;
    }
}

// -------- decoder (R11/R14 proven): 2 blocks/batch x 512 thr; 6 barriers ----
// vw now read from Ycat (row stride 192, offset 128).
__global__ __launch_bounds__(512, 1)
void k_decoder(const float* __restrict__ kqF_g, const float* __restrict__ ycat_g,
               const float* __restrict__ cst_g,
               const float* __restrict__ W1,  const float* __restrict__ b1_g,
               const float* __restrict__ WihL_g, const float* __restrict__ Whh,
               const float* __restrict__ bd_g, u64* gxd,
               float* __restrict__ dec_out, float* __restrict__ attn_w) {
    const int b    = blockIdx.x & 15;
    const int side = blockIdx.x >> 4;     // b and b+16 same XCD
    const int tid  = threadIdx.x;

    __shared__ __align__(16) f4 wih_s[16 * 512];   // 128 KB, lane-contiguous
    __shared__ __align__(16) float tok_s[D0n];
    __shared__ __align__(16) float x_s[Hn];
    __shared__ __align__(16) float h_s[Hn];
    __shared__ float g_loc[256];
    __shared__ float s_s[Ln];
    __shared__ float attn_sp[8][33];               // padded (slab-major)
    __shared__ float cst_s[Ln];
    __shared__ float b1_s[Hn];

    const int rl = tid >> 1, ghalf = tid & 1;      // gates: 256 rows x 2 thr
    const int grow = (rl >> 6) * 128 + side * 64 + (rl & 63);

    // ---- pinned: whh half-row + VW slice + bias ----
    const f4* Whh4 = (const f4*)Whh;
    f4 whh[16];
#pragma unroll
    for (int f = 0; f < 16; ++f) whh[f] = Whh4[(size_t)grow * 32 + ghalf * 16 + f];
    float bdr = bd_g[grow];
    const int o = tid >> 3, slab = tid & 7;        // out phase map
    float vwr[32];
#pragma unroll
    for (int l = 0; l < 32; ++l)
        vwr[l] = ycat_g[((size_t)b * Ln + slab * 32 + l) * 192 + 128 + o];
#pragma unroll
    for (int f = 0; f < 16; ++f) asm volatile("" : "+v"(whh[f]));
#pragma unroll
    for (int l = 0; l < 32; ++l) asm volatile("" : "+v"(vwr[l]));
    asm volatile("" : "+v"(bdr));

    // ---- stage Wih into LDS (coalesced both ends) ----
    const f4* WihL4 = (const f4*)WihL_g;
#pragma unroll
    for (int k = 0; k < 16; ++k)
        wih_s[k * 512 + tid] = WihL4[(size_t)k * 1024 + side * 512 + tid];
    if (tid < D0n) tok_s[tid] = 0.f;
    if (tid < Hn)  { h_s[tid] = 0.f; b1_s[tid] = b1_g[tid]; }
    if (tid < Ln)  cst_s[tid] = cst_g[(size_t)b * Ln + tid];
    float c_reg = 0.f;
    __syncthreads();

    u64* gx_mine = gxd + (b * 2 + side) * 128;
    u64* gx_peer = gxd + (b * 2 + (side ^ 1)) * 128;

    const int ar = tid >> 2, ap = tid & 3;         // x phase: 128 rows x 4 thr
    const f4* W1_4 = (const f4*)W1;
    const f4* kqF  = (const f4*)kqF_g + (size_t)b * 8192;
    const int dbase = (tid & 1) * 16;              // score phase h offset

    for (int t = 0; t < Ln; ++t) {
        // ---- A: x = relu(W1 @ tok + b1); W1 streamed (L2-hot) ----
        {
            const f4* t4 = (const f4*)tok_s;
            float u0 = 0.f, u1 = 0.f;
#pragma unroll
            for (int k = 0; k < 4; k += 2) {
                f4 wa  = W1_4[(size_t)ar * 16 + ap * 4 + k];
                f4 wb2 = W1_4[(size_t)ar * 16 + ap * 4 + k + 1];
                u0 = fma4v(wa,  t4[ap * 4 + k],     u0);
                u1 = fma4v(wb2, t4[ap * 4 + k + 1], u1);
            }
            float a = u0 + u1;
            a += __shfl_xor(a, 1);
            a += __shfl_xor(a, 2);
            if (ap == 0) x_s[ar] = fmaxf(a + b1_s[ar], 0.f);
        }
        __syncthreads();
        // ---- B: gates; Wih from LDS (lane-contig), Whh pinned ----
        {
            const f4* x4 = (const f4*)x_s + ghalf * 16;
            const f4* h4 = (const f4*)h_s + ghalf * 16;
            float a0 = 0.f, a1 = 0.f, a2 = 0.f, a3 = 0.f;
#pragma unroll
            for (int f = 0; f < 16; f += 4) {
                a0 = fma4v(wih_s[f * 512 + tid],       x4[f],     a0);
                a1 = fma4v(wih_s[(f + 1) * 512 + tid], x4[f + 1], a1);
                a2 = fma4v(wih_s[(f + 2) * 512 + tid], x4[f + 2], a2);
                a3 = fma4v(wih_s[(f + 3) * 512 + tid], x4[f + 3], a3);
            }
#pragma unroll
            for (int f = 0; f < 16; f += 4) {
                a0 = fma4v(whh[f],     h4[f],     a0);
                a1 = fma4v(whh[f + 1], h4[f + 1], a1);
                a2 = fma4v(whh[f + 2], h4[f + 2], a2);
                a3 = fma4v(whh[f + 3], h4[f + 3], a3);
            }
            float a = (a0 + a1) + (a2 + a3);
            a += __shfl_xor(a, 1);
            if (ghalf == 0) g_loc[rl] = a + bdr;
        }
        __syncthreads();
        // ---- C: cell (own 64) + tagged publish + poll peer (fused) ----
        if (tid < 64) {
            float ig = sigf(g_loc[tid]);
            float fg = sigf(g_loc[64 + tid]);
            float gg = tanhf(g_loc[128 + tid]);
            float og = sigf(g_loc[192 + tid]);
            c_reg = fg * c_reg + ig * gg;
            float hv = og * tanhf(c_reg);
            h_s[side * 64 + tid] = hv;
            tag_store(&gx_mine[(t & 1) * 64 + tid], hv, (unsigned)(t + 1));
            h_s[(side ^ 1) * 64 + tid] =
                tag_poll(&gx_peer[(t & 1) * 64 + tid], (unsigned)(t + 1));
        }
        __syncthreads();
        // ---- D: scores; KQ streamed coalesced from L2 (L2-hot) ----
        {
            const f4* h4 = (const f4*)h_s;
            float a0 = 0.f, a1 = 0.f;
#pragma unroll
            for (int k = 0; k < 16; k += 2) {
                f4 q0 = kqF[(size_t)k * 512 + tid];
                f4 q1 = kqF[(size_t)(k + 1) * 512 + tid];
                a0 = fma4v(q0, h4[dbase + k],     a0);
                a1 = fma4v(q1, h4[dbase + k + 1], a1);
            }
            float a = a0 + a1;
            a += __shfl_xor(a, 1);
            if ((tid & 1) == 0) s_s[tid >> 1] = a + cst_s[tid >> 1];
        }
        __syncthreads();
        // ---- E: softmax (wave 0); side 0 writes attn_w ----
        if (tid < 64) {
            float v0 = s_s[tid],       v1 = s_s[tid + 64];
            float v2 = s_s[tid + 128], v3 = s_s[tid + 192];
            float m = fmaxf(fmaxf(v0, v1), fmaxf(v2, v3));
#pragma unroll
            for (int o2 = 32; o2 > 0; o2 >>= 1) m = fmaxf(m, __shfl_xor(m, o2));
            float e0 = expf(v0 - m), e1 = expf(v1 - m);
            float e2 = expf(v2 - m), e3 = expf(v3 - m);
            float ss = (e0 + e1) + (e2 + e3);
#pragma unroll
            for (int o2 = 32; o2 > 0; o2 >>= 1) ss += __shfl_xor(ss, o2);
            float inv = 1.f / ss;
            e0 *= inv; e1 *= inv; e2 *= inv; e3 *= inv;
            attn_sp[tid >> 5][tid & 31] = e0;
            attn_sp[(tid + 64) >> 5][tid & 31] = e1;
            attn_sp[(tid + 128) >> 5][tid & 31] = e2;
            attn_sp[(tid + 192) >> 5][tid & 31] = e3;
            if (side == 0) {
                float* aw = attn_w + ((size_t)b * Ln + t) * Ln;
                aw[tid] = e0; aw[tid + 64] = e1;
                aw[tid + 128] = e2; aw[tid + 192] = e3;
            }
        }
        __syncthreads();
        // ---- F: out[o] = sum_l attn[l]*VW'[l][o]; 64 o x 8 slabs ----
        {
            const float* as = attn_sp[slab];
            float g0 = 0.f, g1 = 0.f, g2 = 0.f, g3 = 0.f;
#pragma unroll
            for (int l = 0; l < 32; l += 4) {
                g0 = fmaf(as[l],     vwr[l],     g0);
                g1 = fmaf(as[l + 1], vwr[l + 1], g1);
                g2 = fmaf(as[l + 2], vwr[l + 2], g2);
                g3 = fmaf(as[l + 3], vwr[l + 3], g3);
            }
            float a = (g0 + g1) + (g2 + g3);
            a += __shfl_xor(a, 1);
            a += __shfl_xor(a, 2);
            a += __shfl_xor(a, 4);
            if (slab == 0) {
                tok_s[o] = a;
                if (side == 1) dec_out[((size_t)b * Ln + t) * D0n + o] = a;
            }
        }
        __syncthreads();
    }
}

extern "C" void kernel_launch(void* const* d_in, const int* in_sizes, int n_in,
                              void* d_out, int out_size, void* d_ws, size_t ws_size,
                              hipStream_t stream) {
    const float* inputs     = (const float*)d_in[0];
    const float* in_mask    = (const float*)d_in[2];
    const float* enc_lin1_W = (const float*)d_in[3];
    const float* enc_lin1_b = (const float*)d_in[4];
    const float* enc_Wih_f  = (const float*)d_in[5];
    const float* enc_Whh_f  = (const float*)d_in[6];
    const float* enc_b_f    = (const float*)d_in[7];
    const float* enc_Wih_b  = (const float*)d_in[8];
    const float* enc_Whh_b  = (const float*)d_in[9];
    const float* enc_b_b    = (const float*)d_in[10];
    const float* enc_lin2_W = (const float*)d_in[11];
    const float* enc_lin2_b = (const float*)d_in[12];
    const float* vq_emb     = (const float*)d_in[13];
    const float* dec_lin1_W = (const float*)d_in[14];
    const float* dec_lin1_b = (const float*)d_in[15];
    const float* dec_Wih    = (const float*)d_in[16];
    const float* dec_Whh    = (const float*)d_in[17];
    const float* dec_b      = (const float*)d_in[18];
    const float* attn_Wq    = (const float*)d_in[19];
    const float* attn_bq    = (const float*)d_in[20];
    const float* attn_Wk    = (const float*)d_in[21];
    const float* attn_bk    = (const float*)d_in[22];
    const float* attn_Wv    = (const float*)d_in[23];
    const float* attn_bv    = (const float*)d_in[24];
    const float* dec_lin2_W = (const float*)d_in[25];
    const float* dec_lin2_b = (const float*)d_in[26];

    float* out     = (float*)d_out;
    float* dec_out = out;                       // 16*256*64   = 262144
    float* attn_w  = out + 262144;              // 16*256*256  = 1048576
    float* ze      = out + 1310720;             // 16*256*128  = 524288
    float* zq      = out + 1835008;             // 16*256*128  = 524288

    float* ws    = (float*)d_ws;
    float* enc_x = ws;                          // 524288
    float* xWf   = enc_x + 524288;              // 2097152
    float* xWb   = xWf + 2097152;               // 2097152
    float* hcat  = xWb + 2097152;               // 1048576
    float* base2 = hcat + 1048576;
    float* c2    = base2;                       // 512
    u64*   gxd   = (u64*)(base2 + 512);         // 4096 u64 = 8192 floats
    float* Wcat  = base2 + 512 + 8192;          // 192*128 = 24576
    float* bcat  = Wcat + 24576;                // 256
    float* uvec  = bcat + 256;                  // 128
    float* ubv   = uvec + 128;                  // 16
    float* WihL  = ubv + 16;                    // 65536
    float* WhhL  = WihL + 65536;                // 65536
    // aliases into dead regions:
    float* dist  = xWf;                         // 2097152 (dead after vqpick)
    float* KQF   = xWf;                         // 524288 (dist dead after vqpick)
    float* Ycat  = xWb;                         // 4096*192 = 786432 (xWb dead)
    float* cst   = xWb + 786432;                // 4096

    dim3 blk(256);
    // ---- weight algebra + norms + tag zeroing (independent; first) ----
    k_prep<<<260, 256, 0, stream>>>(attn_Wq, attn_Wk, attn_Wv, dec_lin2_W,
                                    attn_bk, attn_bv, dec_lin2_b, attn_bq,
                                    Wcat, bcat, uvec, ubv,
                                    (const f4*)dec_Wih, (f4*)WihL,
                                    (const f4*)enc_Whh_f, (const f4*)enc_Whh_b,
                                    (f4*)WhhL, vq_emb, c2, (int*)gxd);
    // ---- encoder front ----
    k_gemm<<<dim3(2, 64), blk, 0, stream>>>(inputs, enc_lin1_W, enc_lin1_b, enc_x, D0n, Hn, 1, 1.f);
    k_gemm2<<<dim3(8, 64, 2), blk, 0, stream>>>(enc_x,
                                                enc_Wih_f, enc_b_f, xWf,
                                                enc_Wih_b, enc_b_b, xWb, Hn, H4n);
    // ---- BiLSTM ----
    k_lstm3<<<32, 512, 0, stream>>>(xWf, xWb, enc_Whh_f, enc_Whh_b, WhhL, hcat);
    k_gemm<<<dim3(2, 64), blk, 0, stream>>>(hcat, enc_lin2_W, enc_lin2_b, ze, 2 * Hn, Hn, 0, 1.f);
    // ---- VQ ----
    k_gemm<<<dim3(8, 64), blk, 0, stream>>>(ze, vq_emb, c2, dist, Hn, Kn, 0, -2.f);
    k_vqpick<<<BLn, 128, 0, stream>>>(dist, vq_emb, zq);
    // ---- collapsed attention precomputes: Ycat = zq@Wcat^T + bcat ----
    k_gemm<<<dim3(3, 64), blk, 0, stream>>>(zq, Wcat, bcat, Ycat, Hn, 192, 0, 1.f);
    k_cst<<<Bn, 256, 0, stream>>>(zq, uvec, ubv, in_mask, cst);
    k_rearrKQF<<<512, 256, 0, stream>>>((const f4*)Ycat, (f4*)KQF);
    // ---- decoder: 32 blocks = 16 batches x 2 sides, 512 thr ----
    k_decoder<<<32, 512, 0, stream>>>(KQF, Ycat, cst,
                                      dec_lin1_W, dec_lin1_b,
                                      WihL, dec_Whh, dec_b, gxd,
                                      dec_out, attn_w);
}

// Round 19
// 1542.641 us; speedup vs baseline: 1.1636x; 1.0309x over previous
//
#include <hip/hip_runtime.h>

#define Bn  16
#define Ln  256
#define D0n 64
#define Hn  128
#define H4n 512
#define Kn  512
#define BLn 4096   // Bn*Ln

typedef float f4 __attribute__((ext_vector_type(4)));
typedef unsigned long long u64;

__device__ __forceinline__ float sigf(float x) { return 1.0f / (1.0f + expf(-x)); }

__device__ __forceinline__ float fma4v(f4 w, f4 x, float acc) {
    acc = fmaf(w.x, x.x, acc);
    acc = fmaf(w.y, x.y, acc);
    acc = fmaf(w.z, x.z, acc);
    acc = fmaf(w.w, x.w, acc);
    return acc;
}

__device__ __forceinline__ float dotn(const f4* __restrict__ a,
                                      const f4* __restrict__ w, int n4) {
    float a0 = 0.f, a1 = 0.f, a2 = 0.f, a3 = 0.f;
    for (int i = 0; i < n4; i += 4) {
        a0 = fma4v(a[i], w[i], a0);
        a1 = fma4v(a[i + 1], w[i + 1], a1);
        a2 = fma4v(a[i + 2], w[i + 2], a2);
        a3 = fma4v(a[i + 3], w[i + 3], a3);
    }
    return (a0 + a1) + (a2 + a3);
}

// tagged-payload helpers: (tag<<32) | float bits, single 8B relaxed atomic.
// PROTOCOL INVARIANT: a thread must issue its tag_store BEFORE entering any
// tag_poll spin, in straight-line code within the same lane.
__device__ __forceinline__ void tag_store(u64* p, float v, unsigned tag) {
    u64 pk = ((u64)tag << 32) | (u64)__float_as_uint(v);
    __hip_atomic_store(p, pk, __ATOMIC_RELAXED, __HIP_MEMORY_SCOPE_AGENT);
}
__device__ __forceinline__ float tag_poll(u64* p, unsigned tag) {
    u64 v;
    do {
        v = __hip_atomic_load(p, __ATOMIC_RELAXED, __HIP_MEMORY_SCOPE_AGENT);
    } while ((unsigned)(v >> 32) != tag);
    return __uint_as_float((unsigned)v);
}

// ---- tiled GEMM v3: [k4][c] f4 tile, lane-contiguous b128, 4-row blocking --
__global__ __launch_bounds__(256)
void k_gemm(const float* __restrict__ X, const float* __restrict__ W,
            const float* __restrict__ b, float* __restrict__ Y,
            int K, int out_dim, int do_relu, float scale) {
    __shared__ __align__(16) f4 wt4[4096];   // [k4][64], K<=256
    const int K4 = K >> 2;
    const int tid = threadIdx.x;
    const int c = tid & 63, rpart = tid >> 6;
    const f4* W4 = (const f4*)W;
    const int per = K4 >> 2;
    for (int j = 0; j < per; ++j) {
        int col = rpart * per + j;
        wt4[col * 64 + c] = W4[(size_t)(blockIdx.x * 64 + c) * K4 + col];
    }
    __syncthreads();
    const f4* X4 = (const f4*)X;
    const float bc = b ? b[blockIdx.x * 64 + c] : 0.f;
    const int cidx = blockIdx.x * 64 + c;
    for (int i = 0; i < 4; ++i) {
        int rbase = blockIdx.y * 64 + i * 16 + rpart * 4;
        const f4* xr0 = X4 + (size_t)(rbase + 0) * K4;
        const f4* xr1 = X4 + (size_t)(rbase + 1) * K4;
        const f4* xr2 = X4 + (size_t)(rbase + 2) * K4;
        const f4* xr3 = X4 + (size_t)(rbase + 3) * K4;
        float a0 = 0.f, a1 = 0.f, a2 = 0.f, a3 = 0.f;
        for (int k4 = 0; k4 < K4; ++k4) {
            f4 wv = wt4[k4 * 64 + c];
            a0 = fma4v(wv, xr0[k4], a0);
            a1 = fma4v(wv, xr1[k4], a1);
            a2 = fma4v(wv, xr2[k4], a2);
            a3 = fma4v(wv, xr3[k4], a3);
        }
        a0 = scale * a0 + bc; a1 = scale * a1 + bc;
        a2 = scale * a2 + bc; a3 = scale * a3 + bc;
        if (do_relu) {
            a0 = fmaxf(a0, 0.f); a1 = fmaxf(a1, 0.f);
            a2 = fmaxf(a2, 0.f); a3 = fmaxf(a3, 0.f);
        }
        Y[(size_t)(rbase + 0) * out_dim + cidx] = a0;
        Y[(size_t)(rbase + 1) * out_dim + cidx] = a1;
        Y[(size_t)(rbase + 2) * out_dim + cidx] = a2;
        Y[(size_t)(rbase + 3) * out_dim + cidx] = a3;
    }
}

// ---- dual-weight GEMM: z=0 -> (Wf,bf,Yf), z=1 -> (Wb,bb,Yb); same shape ----
__global__ __launch_bounds__(256)
void k_gemm2(const float* __restrict__ X,
             const float* __restrict__ Wf, const float* __restrict__ bf,
             float* __restrict__ Yf,
             const float* __restrict__ Wb, const float* __restrict__ bb,
             float* __restrict__ Yb, int K, int out_dim) {
    __shared__ __align__(16) f4 wt4[4096];
    const float* W = blockIdx.z ? Wb : Wf;
    const float* bb_ = blockIdx.z ? bb : bf;
    float* Y = blockIdx.z ? Yb : Yf;
    const int K4 = K >> 2;
    const int tid = threadIdx.x;
    const int c = tid & 63, rpart = tid >> 6;
    const f4* W4 = (const f4*)W;
    const int per = K4 >> 2;
    for (int j = 0; j < per; ++j) {
        int col = rpart * per + j;
        wt4[col * 64 + c] = W4[(size_t)(blockIdx.x * 64 + c) * K4 + col];
    }
    __syncthreads();
    const f4* X4 = (const f4*)X;
    const float bc = bb_[blockIdx.x * 64 + c];
    const int cidx = blockIdx.x * 64 + c;
    for (int i = 0; i < 4; ++i) {
        int rbase = blockIdx.y * 64 + i * 16 + rpart * 4;
        const f4* xr0 = X4 + (size_t)(rbase + 0) * K4;
        const f4* xr1 = X4 + (size_t)(rbase + 1) * K4;
        const f4* xr2 = X4 + (size_t)(rbase + 2) * K4;
        const f4* xr3 = X4 + (size_t)(rbase + 3) * K4;
        float a0 = 0.f, a1 = 0.f, a2 = 0.f, a3 = 0.f;
        for (int k4 = 0; k4 < K4; ++k4) {
            f4 wv = wt4[k4 * 64 + c];
            a0 = fma4v(wv, xr0[k4], a0);
            a1 = fma4v(wv, xr1[k4], a1);
            a2 = fma4v(wv, xr2[k4], a2);
            a3 = fma4v(wv, xr3[k4], a3);
        }
        Y[(size_t)(rbase + 0) * out_dim + cidx] = a0 + bc;
        Y[(size_t)(rbase + 1) * out_dim + cidx] = a1 + bc;
        Y[(size_t)(rbase + 2) * out_dim + cidx] = a2 + bc;
        Y[(size_t)(rbase + 3) * out_dim + cidx] = a3 + bc;
    }
}

#define SCL 0.088388347648318447f   // 1/sqrt(128)

// ---- k_prep: ALL weight algebra + codebook norms + tag zeroing -------------
// WhhL now uses the wave-fused LSTM row map: grow(t)=((t&63)>>4)*128+(t>>6)*16+(t&15)
__global__ void k_prep(const float* __restrict__ Wq, const float* __restrict__ Wk,
                       const float* __restrict__ Wv, const float* __restrict__ W2,
                       const float* __restrict__ bk, const float* __restrict__ bv,
                       const float* __restrict__ b2, const float* __restrict__ bq,
                       float* __restrict__ Wcat, float* __restrict__ bcat,
                       float* __restrict__ u, float* __restrict__ ub,
                       const f4* __restrict__ dec_Wih, f4* __restrict__ WihL,
                       const f4* __restrict__ whf, const f4* __restrict__ whb,
                       f4* __restrict__ WhhL,
                       const float* __restrict__ emb, float* __restrict__ c2,
                       int* __restrict__ zbuf) {
    const int blk = blockIdx.x, tid = threadIdx.x;
    if (blk < 64) {
        int idx = blk * 256 + tid;
        int c = idx >> 7, d = idx & 127;
        float acc = 0.f;
        for (int r = 0; r < Hn; ++r)
            acc = fmaf(Wq[(size_t)r * Hn + c], Wk[(size_t)r * Hn + d], acc);
        Wcat[(size_t)c * Hn + d] = SCL * acc;
    } else if (blk < 96) {
        int idx = (blk - 64) * 256 + tid;
        int o = idx >> 7, d = idx & 127;
        float acc = 0.f;
        for (int r = 0; r < Hn; ++r)
            acc = fmaf(W2[(size_t)o * Hn + r], Wv[(size_t)r * Hn + d], acc);
        Wcat[(size_t)(128 + o) * Hn + d] = acc;
    } else if (blk < 160) {                // WihL[k*1024 + side*512 + t]
        int idx = (blk - 96) * 256 + tid;  // 16384
        int t = idx & 511, side = (idx >> 9) & 1, k = idx >> 10;
        int rl = t >> 1;
        int grow = (rl >> 6) * 128 + side * 64 + (rl & 63);
        WihL[idx] = dec_Wih[(size_t)grow * 32 + (t & 1) * 16 + k];
    } else if (blk < 224) {                // WhhL[dir][k][t] wave-fused map
        int idx = (blk - 160) * 256 + tid; // 16384
        int t = idx & 511, k = (idx >> 9) & 15, dir = idx >> 13;
        int grow = ((t & 63) >> 4) * 128 + (t >> 6) * 16 + (t & 15);
        const f4* src = dir ? whb : whf;
        WhhL[idx] = src[(size_t)grow * 32 + 16 + k];
    } else if (blk == 224) {
        if (tid < 128) {
            float acc = 0.f;
            for (int r = 0; r < Hn; ++r)
                acc = fmaf(Wq[(size_t)r * Hn + tid], bk[r], acc);
            bcat[tid] = SCL * acc;
        } else if (tid < 192) {
            int o = tid - 128;
            float acc = b2[o];
            for (int r = 0; r < Hn; ++r)
                acc = fmaf(W2[(size_t)o * Hn + r], bv[r], acc);
            bcat[tid] = acc;
        }
    } else if (blk == 225) {
        if (tid < 128) {
            float acc = 0.f;
            for (int r = 0; r < Hn; ++r)
                acc = fmaf(bq[r], Wk[(size_t)r * Hn + tid], acc);
            u[tid] = SCL * acc;
        } else if (tid == 128) {
            float acc = 0.f;
            for (int r = 0; r < Hn; ++r) acc = fmaf(bq[r], bk[r], acc);
            ub[0] = SCL * acc;
        }
    } else if (blk < 228) {
        int k = (blk - 226) * 256 + tid;
        if (k < Kn) {
            const f4* e4 = (const f4*)(emb + (size_t)k * Hn);
            float acc = 0.f;
            for (int i = 0; i < Hn / 4; ++i) {
                f4 v = e4[i];
                acc = fmaf(v.x, v.x, acc); acc = fmaf(v.y, v.y, acc);
                acc = fmaf(v.z, v.z, acc); acc = fmaf(v.w, v.w, acc);
            }
            c2[k] = acc;
        }
    } else {
        int idx = (blk - 228) * 256 + tid;
        if (idx < 8192) zbuf[idx] = 0;
    }
}

// ---- KQF[b][k][tid] = Ycat[b*256 + (tid>>1)][(tid&1)*16 + k], row=48 f4 ----
__global__ void k_rearrKQF(const f4* __restrict__ in, f4* __restrict__ out) {
    int idx = blockIdx.x * blockDim.x + threadIdx.x;   // 131072
    if (idx >= 131072) return;
    int tid = idx & 511, k = (idx >> 9) & 15, b = idx >> 13;
    out[idx] = in[((size_t)b * 256 + (tid >> 1)) * 48 + (tid & 1) * 16 + k];
}

// -------- cst[p] = u . zq[p] + ub + (mask[p]==0 ? -1e9 : 0) --------
__global__ void k_cst(const float* __restrict__ zq, const float* __restrict__ u,
                      const float* __restrict__ ub, const float* __restrict__ mask,
                      float* __restrict__ cst) {
    int p = blockIdx.x * blockDim.x + threadIdx.x;
    if (p >= BLn) return;
    float a = dotn((const f4*)u, (const f4*)(zq + (size_t)p * Hn), Hn >> 2);
    cst[p] = a + ub[0] + (mask[p] == 0.f ? -1e9f : 0.f);
}

// -------- VQ pick: argmin over dist row (first-index ties) + gather ---------
__global__ __launch_bounds__(128)
void k_vqpick(const float* __restrict__ dist, const float* __restrict__ emb,
              float* __restrict__ zq) {
    const int p = blockIdx.x, tid = threadIdx.x;
    __shared__ int best_s;
    if (tid < 64) {
        float best = 3.0e38f; int bi = 0;
        for (int j = 0; j < 8; ++j) {
            int k = j * 64 + tid;
            float d = dist[(size_t)p * Kn + k];
            if (d < best) { best = d; bi = k; }
        }
        for (int off = 32; off > 0; off >>= 1) {
            float ov = __shfl_xor(best, off);
            int   oi = __shfl_xor(bi, off);
            if (ov < best || (ov == best && oi < bi)) { best = ov; bi = oi; }
        }
        if (tid == 0) best_s = bi;
    }
    __syncthreads();
    zq[(size_t)p * Hn + tid] = emb[(size_t)best_s * Hn + tid];
}

// -------- LSTM v4: wave-fused, ONE barrier/step -----------------------------
// tid = w*64 + lane, lane = q*16 + j; gate row = q*128 + w*16 + j.
// Wave w owns comps [w*16, w*16+16): gates gathered via 3 shfl, cell in
// lanes q==0, no g LDS roundtrip. Whh: first half pinned, second half LDS.
__global__ __launch_bounds__(512, 1)
void k_lstm4(const float* __restrict__ xWf, const float* __restrict__ xWb,
             const float* __restrict__ Whh_f, const float* __restrict__ Whh_b,
             const float* __restrict__ WhhL_g, float* __restrict__ hcat) {
    const int b   = blockIdx.x & 15;
    const int dir = blockIdx.x >> 4;
    const int tid = threadIdx.x;
    const int w   = tid >> 6, lane = tid & 63;
    const int q   = lane >> 4, j = lane & 15;
    const int grow = q * 128 + w * 16 + j;
    const float* xW  = dir ? xWb : xWf;
    const f4* Whh4   = (const f4*)(dir ? Whh_b : Whh_f);

    __shared__ __align__(16) f4 wh2_s[16 * 512];   // 128 KB second halves
    __shared__ __align__(16) float h_s[Hn];

    f4 wpin[16];
#pragma unroll
    for (int f = 0; f < 16; ++f) wpin[f] = Whh4[(size_t)grow * 32 + f];
#pragma unroll
    for (int f = 0; f < 16; ++f) asm volatile("" : "+v"(wpin[f]));

    const f4* WhhL4 = (const f4*)WhhL_g;
#pragma unroll
    for (int k = 0; k < 16; ++k)
        wh2_s[k * 512 + tid] = WhhL4[(size_t)dir * 8192 + k * 512 + tid];

    float c_reg = 0.f;
    if (tid < Hn) h_s[tid] = 0.f;

    const int t0 = dir ? (Ln - 1) : 0;
    float xw_v = xW[((size_t)b * Ln + t0) * H4n + grow];
    __syncthreads();

    for (int s = 0; s < Ln; ++s) {
        const int t = dir ? (Ln - 1 - s) : s;
        float xw_n = 0.f;
        if (s + 1 < Ln) {
            int tn = dir ? (Ln - 2 - s) : (s + 1);
            xw_n = xW[((size_t)b * Ln + tn) * H4n + grow];
        }
        float g;
        {
            const f4* h4 = (const f4*)h_s;
            float a0 = 0.f, a1 = 0.f, a2 = 0.f, a3 = 0.f;
#pragma unroll
            for (int f = 0; f < 16; f += 4) {               // h[0:64) pinned
                a0 = fma4v(wpin[f],     h4[f],     a0);
                a1 = fma4v(wpin[f + 1], h4[f + 1], a1);
                a2 = fma4v(wpin[f + 2], h4[f + 2], a2);
                a3 = fma4v(wpin[f + 3], h4[f + 3], a3);
            }
#pragma unroll
            for (int f = 0; f < 16; f += 4) {               // h[64:128) LDS
                a0 = fma4v(wh2_s[f * 512 + tid],       h4[16 + f],     a0);
                a1 = fma4v(wh2_s[(f + 1) * 512 + tid], h4[16 + f + 1], a1);
                a2 = fma4v(wh2_s[(f + 2) * 512 + tid], h4[16 + f + 2], a2);
                a3 = fma4v(wh2_s[(f + 3) * 512 + tid], h4[16 + f + 3], a3);
            }
            g = (a0 + a1) + (a2 + a3) + xw_v;
        }
        // gather i,f,g,o for component w*16+j from lanes j, 16+j, 32+j, 48+j
        float gI = __shfl(g, j);
        float gF = __shfl(g, 16 + j);
        float gG = __shfl(g, 32 + j);
        float gO = __shfl(g, 48 + j);
        if (q == 0) {
            float ig = sigf(gI), fg = sigf(gF);
            float gg = tanhf(gG), og = sigf(gO);
            c_reg = fg * c_reg + ig * gg;
            float hv = og * tanhf(c_reg);
            int cc = w * 16 + j;
            h_s[cc] = hv;
            hcat[((size_t)b * Ln + t) * (2 * Hn) + dir * Hn + cc] = hv;
        }
        __syncthreads();
        xw_v = xw_n;
    }
}

// -------- decoder (R11/R14 proven): 2 blocks/batch x 512 thr; 6 barriers ----
// vw read from Ycat (row stride 192, offset 128).
__global__ __launch_bounds__(512, 1)
void k_decoder(const float* __restrict__ kqF_g, const float* __restrict__ ycat_g,
               const float* __restrict__ cst_g,
               const float* __restrict__ W1,  const float* __restrict__ b1_g,
               const float* __restrict__ WihL_g, const float* __restrict__ Whh,
               const float* __restrict__ bd_g, u64* gxd,
               float* __restrict__ dec_out, float* __restrict__ attn_w) {
    const int b    = blockIdx.x & 15;
    const int side = blockIdx.x >> 4;     // b and b+16 same XCD
    const int tid  = threadIdx.x;

    __shared__ __align__(16) f4 wih_s[16 * 512];   // 128 KB, lane-contiguous
    __shared__ __align__(16) float tok_s[D0n];
    __shared__ __align__(16) float x_s[Hn];
    __shared__ __align__(16) float h_s[Hn];
    __shared__ float g_loc[256];
    __shared__ float s_s[Ln];
    __shared__ float attn_sp[8][33];               // padded (slab-major)
    __shared__ float cst_s[Ln];
    __shared__ float b1_s[Hn];

    const int rl = tid >> 1, ghalf = tid & 1;      // gates: 256 rows x 2 thr
    const int grow = (rl >> 6) * 128 + side * 64 + (rl & 63);

    // ---- pinned: whh half-row + VW slice + bias ----
    const f4* Whh4 = (const f4*)Whh;
    f4 whh[16];
#pragma unroll
    for (int f = 0; f < 16; ++f) whh[f] = Whh4[(size_t)grow * 32 + ghalf * 16 + f];
    float bdr = bd_g[grow];
    const int o = tid >> 3, slab = tid & 7;        // out phase map
    float vwr[32];
#pragma unroll
    for (int l = 0; l < 32; ++l)
        vwr[l] = ycat_g[((size_t)b * Ln + slab * 32 + l) * 192 + 128 + o];
#pragma unroll
    for (int f = 0; f < 16; ++f) asm volatile("" : "+v"(whh[f]));
#pragma unroll
    for (int l = 0; l < 32; ++l) asm volatile("" : "+v"(vwr[l]));
    asm volatile("" : "+v"(bdr));

    // ---- stage Wih into LDS (coalesced both ends) ----
    const f4* WihL4 = (const f4*)WihL_g;
#pragma unroll
    for (int k = 0; k < 16; ++k)
        wih_s[k * 512 + tid] = WihL4[(size_t)k * 1024 + side * 512 + tid];
    if (tid < D0n) tok_s[tid] = 0.f;
    if (tid < Hn)  { h_s[tid] = 0.f; b1_s[tid] = b1_g[tid]; }
    if (tid < Ln)  cst_s[tid] = cst_g[(size_t)b * Ln + tid];
    float c_reg = 0.f;
    __syncthreads();

    u64* gx_mine = gxd + (b * 2 + side) * 128;
    u64* gx_peer = gxd + (b * 2 + (side ^ 1)) * 128;

    const int ar = tid >> 2, ap = tid & 3;         // x phase: 128 rows x 4 thr
    const f4* W1_4 = (const f4*)W1;
    const f4* kqF  = (const f4*)kqF_g + (size_t)b * 8192;
    const int dbase = (tid & 1) * 16;              // score phase h offset

    for (int t = 0; t < Ln; ++t) {
        // ---- A: x = relu(W1 @ tok + b1); W1 streamed (L2-hot) ----
        {
            const f4* t4 = (const f4*)tok_s;
            float u0 = 0.f, u1 = 0.f;
#pragma unroll
            for (int k = 0; k < 4; k += 2) {
                f4 wa  = W1_4[(size_t)ar * 16 + ap * 4 + k];
                f4 wb2 = W1_4[(size_t)ar * 16 + ap * 4 + k + 1];
                u0 = fma4v(wa,  t4[ap * 4 + k],     u0);
                u1 = fma4v(wb2, t4[ap * 4 + k + 1], u1);
            }
            float a = u0 + u1;
            a += __shfl_xor(a, 1);
            a += __shfl_xor(a, 2);
            if (ap == 0) x_s[ar] = fmaxf(a + b1_s[ar], 0.f);
        }
        __syncthreads();
        // ---- B: gates; Wih from LDS (lane-contig), Whh pinned ----
        {
            const f4* x4 = (const f4*)x_s + ghalf * 16;
            const f4* h4 = (const f4*)h_s + ghalf * 16;
            float a0 = 0.f, a1 = 0.f, a2 = 0.f, a3 = 0.f;
#pragma unroll
            for (int f = 0; f < 16; f += 4) {
                a0 = fma4v(wih_s[f * 512 + tid],       x4[f],     a0);
                a1 = fma4v(wih_s[(f + 1) * 512 + tid], x4[f + 1], a1);
                a2 = fma4v(wih_s[(f + 2) * 512 + tid], x4[f + 2], a2);
                a3 = fma4v(wih_s[(f + 3) * 512 + tid], x4[f + 3], a3);
            }
#pragma unroll
            for (int f = 0; f < 16; f += 4) {
                a0 = fma4v(whh[f],     h4[f],     a0);
                a1 = fma4v(whh[f + 1], h4[f + 1], a1);
                a2 = fma4v(whh[f + 2], h4[f + 2], a2);
                a3 = fma4v(whh[f + 3], h4[f + 3], a3);
            }
            float a = (a0 + a1) + (a2 + a3);
            a += __shfl_xor(a, 1);
            if (ghalf == 0) g_loc[rl] = a + bdr;
        }
        __syncthreads();
        // ---- C: cell (own 64) + tagged publish + poll peer (fused) ----
        if (tid < 64) {
            float ig = sigf(g_loc[tid]);
            float fg = sigf(g_loc[64 + tid]);
            float gg = tanhf(g_loc[128 + tid]);
            float og = sigf(g_loc[192 + tid]);
            c_reg = fg * c_reg + ig * gg;
            float hv = og * tanhf(c_reg);
            h_s[side * 64 + tid] = hv;
            tag_store(&gx_mine[(t & 1) * 64 + tid], hv, (unsigned)(t + 1));
            h_s[(side ^ 1) * 64 + tid] =
                tag_poll(&gx_peer[(t & 1) * 64 + tid], (unsigned)(t + 1));
        }
        __syncthreads();
        // ---- D: scores; KQ streamed coalesced from L2 (L2-hot) ----
        {
            const f4* h4 = (const f4*)h_s;
            float a0 = 0.f, a1 = 0.f;
#pragma unroll
            for (int k = 0; k < 16; k += 2) {
                f4 q0 = kqF[(size_t)k * 512 + tid];
                f4 q1 = kqF[(size_t)(k + 1) * 512 + tid];
                a0 = fma4v(q0, h4[dbase + k],     a0);
                a1 = fma4v(q1, h4[dbase + k + 1], a1);
            }
            float a = a0 + a1;
            a += __shfl_xor(a, 1);
            if ((tid & 1) == 0) s_s[tid >> 1] = a + cst_s[tid >> 1];
        }
        __syncthreads();
        // ---- E: softmax (wave 0); side 0 writes attn_w ----
        if (tid < 64) {
            float v0 = s_s[tid],       v1 = s_s[tid + 64];
            float v2 = s_s[tid + 128], v3 = s_s[tid + 192];
            float m = fmaxf(fmaxf(v0, v1), fmaxf(v2, v3));
#pragma unroll
            for (int o2 = 32; o2 > 0; o2 >>= 1) m = fmaxf(m, __shfl_xor(m, o2));
            float e0 = expf(v0 - m), e1 = expf(v1 - m);
            float e2 = expf(v2 - m), e3 = expf(v3 - m);
            float ss = (e0 + e1) + (e2 + e3);
#pragma unroll
            for (int o2 = 32; o2 > 0; o2 >>= 1) ss += __shfl_xor(ss, o2);
            float inv = 1.f / ss;
            e0 *= inv; e1 *= inv; e2 *= inv; e3 *= inv;
            attn_sp[tid >> 5][tid & 31] = e0;
            attn_sp[(tid + 64) >> 5][tid & 31] = e1;
            attn_sp[(tid + 128) >> 5][tid & 31] = e2;
            attn_sp[(tid + 192) >> 5][tid & 31] = e3;
            if (side == 0) {
                float* aw = attn_w + ((size_t)b * Ln + t) * Ln;
                aw[tid] = e0; aw[tid + 64] = e1;
                aw[tid + 128] = e2; aw[tid + 192] = e3;
            }
        }
        __syncthreads();
        // ---- F: out[o] = sum_l attn[l]*VW'[l][o]; 64 o x 8 slabs ----
        {
            const float* as = attn_sp[slab];
            float g0 = 0.f, g1 = 0.f, g2 = 0.f, g3 = 0.f;
#pragma unroll
            for (int l = 0; l < 32; l += 4) {
                g0 = fmaf(as[l],     vwr[l],     g0);
                g1 = fmaf(as[l + 1], vwr[l + 1], g1);
                g2 = fmaf(as[l + 2], vwr[l + 2], g2);
                g3 = fmaf(as[l + 3], vwr[l + 3], g3);
            }
            float a = (g0 + g1) + (g2 + g3);
            a += __shfl_xor(a, 1);
            a += __shfl_xor(a, 2);
            a += __shfl_xor(a, 4);
            if (slab == 0) {
                tok_s[o] = a;
                if (side == 1) dec_out[((size_t)b * Ln + t) * D0n + o] = a;
            }
        }
        __syncthreads();
    }
}

extern "C" void kernel_launch(void* const* d_in, const int* in_sizes, int n_in,
                              void* d_out, int out_size, void* d_ws, size_t ws_size,
                              hipStream_t stream) {
    const float* inputs     = (const float*)d_in[0];
    const float* in_mask    = (const float*)d_in[2];
    const float* enc_lin1_W = (const float*)d_in[3];
    const float* enc_lin1_b = (const float*)d_in[4];
    const float* enc_Wih_f  = (const float*)d_in[5];
    const float* enc_Whh_f  = (const float*)d_in[6];
    const float* enc_b_f    = (const float*)d_in[7];
    const float* enc_Wih_b  = (const float*)d_in[8];
    const float* enc_Whh_b  = (const float*)d_in[9];
    const float* enc_b_b    = (const float*)d_in[10];
    const float* enc_lin2_W = (const float*)d_in[11];
    const float* enc_lin2_b = (const float*)d_in[12];
    const float* vq_emb     = (const float*)d_in[13];
    const float* dec_lin1_W = (const float*)d_in[14];
    const float* dec_lin1_b = (const float*)d_in[15];
    const float* dec_Wih    = (const float*)d_in[16];
    const float* dec_Whh    = (const float*)d_in[17];
    const float* dec_b      = (const float*)d_in[18];
    const float* attn_Wq    = (const float*)d_in[19];
    const float* attn_bq    = (const float*)d_in[20];
    const float* attn_Wk    = (const float*)d_in[21];
    const float* attn_bk    = (const float*)d_in[22];
    const float* attn_Wv    = (const float*)d_in[23];
    const float* attn_bv    = (const float*)d_in[24];
    const float* dec_lin2_W = (const float*)d_in[25];
    const float* dec_lin2_b = (const float*)d_in[26];

    float* out     = (float*)d_out;
    float* dec_out = out;                       // 16*256*64   = 262144
    float* attn_w  = out + 262144;              // 16*256*256  = 1048576
    float* ze      = out + 1310720;             // 16*256*128  = 524288
    float* zq      = out + 1835008;             // 16*256*128  = 524288

    float* ws    = (float*)d_ws;
    float* enc_x = ws;                          // 524288
    float* xWf   = enc_x + 524288;              // 2097152
    float* xWb   = xWf + 2097152;               // 2097152
    float* hcat  = xWb + 2097152;               // 1048576
    float* base2 = hcat + 1048576;
    float* c2    = base2;                       // 512
    u64*   gxd   = (u64*)(base2 + 512);         // 4096 u64 = 8192 floats
    float* Wcat  = base2 + 512 + 8192;          // 192*128 = 24576
    float* bcat  = Wcat + 24576;                // 256
    float* uvec  = bcat + 256;                  // 128
    float* ubv   = uvec + 128;                  // 16
    float* WihL  = ubv + 16;                    // 65536
    float* WhhL  = WihL + 65536;                // 65536
    // aliases into dead regions:
    float* dist  = xWf;                         // 2097152 (dead after vqpick)
    float* KQF   = xWf;                         // 524288 (dist dead after vqpick)
    float* Ycat  = xWb;                         // 4096*192 = 786432 (xWb dead)
    float* cst   = xWb + 786432;                // 4096

    dim3 blk(256);
    // ---- weight algebra + norms + tag zeroing (independent; first) ----
    k_prep<<<260, 256, 0, stream>>>(attn_Wq, attn_Wk, attn_Wv, dec_lin2_W,
                                    attn_bk, attn_bv, dec_lin2_b, attn_bq,
                                    Wcat, bcat, uvec, ubv,
                                    (const f4*)dec_Wih, (f4*)WihL,
                                    (const f4*)enc_Whh_f, (const f4*)enc_Whh_b,
                                    (f4*)WhhL, vq_emb, c2, (int*)gxd);
    // ---- encoder front ----
    k_gemm<<<dim3(2, 64), blk, 0, stream>>>(inputs, enc_lin1_W, enc_lin1_b, enc_x, D0n, Hn, 1, 1.f);
    k_gemm2<<<dim3(8, 64, 2), blk, 0, stream>>>(enc_x,
                                                enc_Wih_f, enc_b_f, xWf,
                                                enc_Wih_b, enc_b_b, xWb, Hn, H4n);
    // ---- BiLSTM: wave-fused, 1 barrier/step ----
    k_lstm4<<<32, 512, 0, stream>>>(xWf, xWb, enc_Whh_f, enc_Whh_b, WhhL, hcat);
    k_gemm<<<dim3(2, 64), blk, 0, stream>>>(hcat, enc_lin2_W, enc_lin2_b, ze, 2 * Hn, Hn, 0, 1.f);
    // ---- VQ ----
    k_gemm<<<dim3(8, 64), blk, 0, stream>>>(ze, vq_emb, c2, dist, Hn, Kn, 0, -2.f);
    k_vqpick<<<BLn, 128, 0, stream>>>(dist, vq_emb, zq);
    // ---- collapsed attention precomputes: Ycat = zq@Wcat^T + bcat ----
    k_gemm<<<dim3(3, 64), blk, 0, stream>>>(zq, Wcat, bcat, Ycat, Hn, 192, 0, 1.f);
    k_cst<<<Bn, 256, 0, stream>>>(zq, uvec, ubv, in_mask, cst);
    k_rearrKQF<<<512, 256, 0, stream>>>((const f4*)Ycat, (f4*)KQF);
    // ---- decoder: 32 blocks = 16 batches x 2 sides, 512 thr ----
    k_decoder<<<32, 512, 0, stream>>>(KQF, Ycat, cst,
                                      dec_lin1_W, dec_lin1_b,
                                      WihL, dec_Whh, dec_b, gxd,
                                      dec_out, attn_w);
}